// Round 3
// baseline (4648.292 us; speedup 1.0000x reference)
//
#include <hip/hip_runtime.h>
#include <math.h>

#define N_ENTITY 200000
#define EMBED    64
#define N_EDGES  6400000
#define BATCH    1024
#define QLEN     20
#define NNEG     5
#define NSEL     (BATCH + BATCH + BATCH*NNEG)   // 7168 gathered rows
#define BM_WORDS ((N_ENTITY + 31) / 32)

#define BROWS     128                            // rows per bucket
#define NBUCKET   ((N_ENTITY + BROWS - 1) / BROWS)   // 1563
#define NBLK_PART 192

// ---------------------------------------------- sel helpers ---------------
__device__ __forceinline__ int sel_row(int i, const int* users, const int* items,
                                       const int* negs) {
    if (i < BATCH)        return users[i];
    if (i < 2 * BATCH)    return items[i - BATCH];
    return negs[i - 2 * BATCH];
}

__global__ void mark_sel_kernel(const int* __restrict__ users,
                                const int* __restrict__ items,
                                const int* __restrict__ negs,
                                unsigned int* __restrict__ bmSel,
                                unsigned int* __restrict__ bmNeed) {
    int i = blockIdx.x * blockDim.x + threadIdx.x;
    if (i >= NSEL) return;
    int idx = sel_row(i, users, items, negs);
    atomicOr(&bmSel[idx >> 5],  1u << (idx & 31));
    atomicOr(&bmNeed[idx >> 5], 1u << (idx & 31));   // self term for sel_accum(hB)
}

// ------------------------------------------------------ edge partition ----
__global__ void part_hist_kernel(const int* __restrict__ erow,
                                 int* __restrict__ bucket_cnt,
                                 int* __restrict__ blockBase) {
    __shared__ int h[NBUCKET];
    int blk = blockIdx.x, t = threadIdx.x;
    for (int i = t; i < NBUCKET; i += 256) h[i] = 0;
    __syncthreads();
    int per = (N_EDGES + NBLK_PART - 1) / NBLK_PART;
    int s = blk * per, e = min(s + per, N_EDGES);
    for (int j = s + t; j < e; j += 256)
        atomicAdd(&h[erow[j] >> 7], 1);
    __syncthreads();
    for (int i = t; i < NBUCKET; i += 256)
        blockBase[blk * NBUCKET + i] = atomicAdd(&bucket_cnt[i], h[i]);
}

__global__ void bucket_scan_kernel(const int* __restrict__ cnt,
                                   int* __restrict__ bstart) {
    __shared__ int s[256];
    int t = threadIdx.x;
    int loc[7];
    int sum = 0;
    #pragma unroll
    for (int k = 0; k < 7; ++k) {
        int i = t * 7 + k;
        int c = (i < NBUCKET) ? cnt[i] : 0;
        loc[k] = sum; sum += c;
    }
    s[t] = sum; __syncthreads();
    for (int off = 1; off < 256; off <<= 1) {
        int x = (t >= off) ? s[t - off] : 0;
        __syncthreads();
        s[t] += x;
        __syncthreads();
    }
    int excl = t ? s[t - 1] : 0;
    #pragma unroll
    for (int k = 0; k < 7; ++k) {
        int i = t * 7 + k;
        if (i < NBUCKET) bstart[i] = excl + loc[k];
    }
    if (t == 255) bstart[NBUCKET] = excl + sum;   // = N_EDGES
}

// scatter into bucket-grouped buffer; fuse bmNeed marking (cols of sel rows)
__global__ void part_scatter_kernel(const int* __restrict__ erow,
                                    const int* __restrict__ ecol,
                                    const float* __restrict__ evalv,
                                    const int* __restrict__ bstart,
                                    const int* __restrict__ blockBase,
                                    const unsigned int* __restrict__ bmSel,
                                    unsigned int* __restrict__ bmNeed,
                                    int2* __restrict__ ebuf) {
    __shared__ int cur[NBUCKET];
    int blk = blockIdx.x, t = threadIdx.x;
    for (int i = t; i < NBUCKET; i += 256)
        cur[i] = bstart[i] + blockBase[blk * NBUCKET + i];
    __syncthreads();
    int per = (N_EDGES + NBLK_PART - 1) / NBLK_PART;
    int s = blk * per, e = min(s + per, N_EDGES);
    for (int j = s + t; j < e; j += 256) {
        int   r = erow[j];
        int   c = ecol[j];
        float v = evalv[j];
        int pos = atomicAdd(&cur[r >> 7], 1);            // LDS atomic
        ebuf[pos] = make_int2(c | ((r & 127) << 18), __float_as_int(v));
        if ((bmSel[r >> 5] >> (r & 31)) & 1u)
            atomicOr(&bmNeed[c >> 5], 1u << (c & 31));
    }
}

// ---------------------------------------------------- bucket SpMM ---------
// FILTER=0: all rows. FILTER=1: only rows whose bm bit is set (skip + write).
template<int FILTER>
__global__ void spmm_bucket_kernel(const float* __restrict__ src,
                                   float* __restrict__ dst,
                                   const int* __restrict__ bstart,
                                   const int2* __restrict__ ebuf,
                                   const unsigned int* __restrict__ bm) {
    __shared__ float acc[BROWS][EMBED];    // 32 KB
    int b    = blockIdx.x;
    int t    = threadIdx.x;
    int lane = t & 63;
    int wv   = t >> 6;                     // 4 waves/block
    for (int i = t; i < BROWS * EMBED; i += 256) ((float*)acc)[i] = 0.f;
    __syncthreads();

    int beg = bstart[b], end = bstart[b + 1];
    if (FILTER == 0) {
        int j = beg + wv;
        while (j < end) {
            int2 e0 = ebuf[j];
            int  j1 = j + 4;
            bool h2 = j1 < end;
            int2 e1 = h2 ? ebuf[j1] : make_int2(0, 0);
            int   p0 = e0.x; float v0 = __int_as_float(e0.y);
            float x0 = src[(size_t)(p0 & 0x3FFFF) * EMBED + lane];
            if (h2) {
                int   p1 = e1.x; float v1 = __int_as_float(e1.y);
                float x1 = src[(size_t)(p1 & 0x3FFFF) * EMBED + lane];
                atomicAdd(&acc[p0 >> 18][lane], v0 * x0);
                atomicAdd(&acc[p1 >> 18][lane], v1 * x1);
            } else {
                atomicAdd(&acc[p0 >> 18][lane], v0 * x0);
            }
            j += 8;
        }
    } else {
        // ballot-compacted scan: lane-per-edge load, process only active lanes
        for (int cb = beg + wv * 64; cb < end; cb += 256) {
            int  j     = cb + lane;
            bool valid = j < end;
            int2 e = valid ? ebuf[j] : make_int2(0, 0);
            int   p  = e.x;
            float vv = __int_as_float(e.y);
            int  row = (b << 7) + (p >> 18);
            bool act = valid && ((bm[row >> 5] >> (row & 31)) & 1u);
            unsigned long long m = __ballot(act);
            while (m) {
                int l0 = __ffsll(m) - 1; m &= m - 1;
                int l1 = -1;
                if (m) { l1 = __ffsll(m) - 1; m &= m - 1; }
                int   pp0 = __shfl(p, l0);
                float vv0 = __shfl(vv, l0);
                float x0  = src[(size_t)(pp0 & 0x3FFFF) * EMBED + lane];
                if (l1 >= 0) {
                    int   pp1 = __shfl(p, l1);
                    float vv1 = __shfl(vv, l1);
                    float x1  = src[(size_t)(pp1 & 0x3FFFF) * EMBED + lane];
                    atomicAdd(&acc[pp0 >> 18][lane], vv0 * x0);
                    atomicAdd(&acc[pp1 >> 18][lane], vv1 * x1);
                } else {
                    atomicAdd(&acc[pp0 >> 18][lane], vv0 * x0);
                }
            }
        }
    }
    __syncthreads();

    for (int rl = wv; rl < BROWS; rl += 4) {
        int r = (b << 7) + rl;
        if (r >= N_ENTITY) continue;
        if (FILTER && !((bm[r >> 5] >> (r & 31)) & 1u)) continue;
        dst[(size_t)r * EMBED + lane] = acc[rl][lane];
    }
}

// ------------------------------------------------- sel accumulate ---------
__global__ void sel_accum_kernel(const float* __restrict__ h,
                                 const int* __restrict__ users,
                                 const int* __restrict__ items,
                                 const int* __restrict__ negs,
                                 float* __restrict__ sel, int init) {
    int tid = blockIdx.x * blockDim.x + threadIdx.x;
    if (tid >= NSEL * EMBED) return;
    int i = tid >> 6, d = tid & 63;
    int idx = sel_row(i, users, items, negs);
    float v = h[(size_t)idx * EMBED + d];
    if (init) sel[tid] = v;
    else      sel[tid] += v;
}

// --------------------------------------- fallback (atomic) path -----------
__global__ void spmm_kernel(const float* __restrict__ src, float* __restrict__ dst,
                            const int* __restrict__ erow, const int* __restrict__ ecol,
                            const float* __restrict__ evalv, int n_edges) {
    int lane  = threadIdx.x & 63;
    int wave  = blockIdx.x * (blockDim.x >> 6) + (threadIdx.x >> 6);
    int nwave = gridDim.x * (blockDim.x >> 6);
    for (int e = wave; e < n_edges; e += nwave) {
        int   r = erow[e];
        int   c = ecol[e];
        float v = evalv[e];
        float x = src[(size_t)c * EMBED + lane];
        atomicAdd(&dst[(size_t)r * EMBED + lane], v * x);
    }
}

__global__ void spmm_filtered_kernel(const float* __restrict__ src, float* __restrict__ dst,
                                     const int* __restrict__ erow, const int* __restrict__ ecol,
                                     const float* __restrict__ evalv,
                                     const unsigned int* __restrict__ bm, int n_edges) {
    int lane  = threadIdx.x & 63;
    int wave  = blockIdx.x * (blockDim.x >> 6) + (threadIdx.x >> 6);
    int nwave = gridDim.x * (blockDim.x >> 6);
    for (int e = wave; e < n_edges; e += nwave) {
        int r = erow[e];
        if (!((bm[r >> 5] >> (r & 31)) & 1u)) continue;
        int   c = ecol[e];
        float v = evalv[e];
        float x = src[(size_t)c * EMBED + lane];
        atomicAdd(&dst[(size_t)r * EMBED + lane], v * x);
    }
}

__global__ void bitmap_build_kernel(const int* __restrict__ users,
                                    const int* __restrict__ items,
                                    const int* __restrict__ negs,
                                    unsigned int* __restrict__ bm) {
    int i = blockIdx.x * blockDim.x + threadIdx.x;
    if (i >= NSEL) return;
    int idx = sel_row(i, users, items, negs);
    atomicOr(&bm[idx >> 5], 1u << (idx & 31));
}

// -------------------------------------------------------- sentence encode --
__global__ void sent_kernel(const int* __restrict__ qwords,
                            const float* __restrict__ word_w,
                            const float* __restrict__ Win,  const float* __restrict__ bin,
                            const float* __restrict__ Wout, const float* __restrict__ bout,
                            float* __restrict__ qenc) {
    __shared__ float x[QLEN][EMBED];
    __shared__ float qkv[QLEN][3*EMBED];
    __shared__ float ctx[QLEN][EMBED];
    __shared__ float mctx[EMBED];
    int b = blockIdx.x;
    int t = threadIdx.x;   // 0..127

    for (int j = t; j < QLEN*EMBED; j += 128) {
        int q = j >> 6, d = j & 63;
        int w = qwords[b*QLEN + q];
        x[q][d] = word_w[(size_t)w * EMBED + d];
    }
    __syncthreads();

    for (int j = t; j < QLEN*192; j += 128) {
        int q = j / 192, o = j % 192;
        float acc = bin[o];
        const float* wrow = &Win[o*EMBED];
        #pragma unroll
        for (int d = 0; d < EMBED; ++d) acc += x[q][d] * wrow[d];
        qkv[q][o] = acc;
    }
    __syncthreads();

    if (t < 4*QLEN) {
        int h = t / QLEN, i = t % QLEN;
        float sc[QLEN];
        float mx = -1e30f;
        #pragma unroll
        for (int k = 0; k < QLEN; ++k) {
            float s = 0.f;
            #pragma unroll
            for (int d = 0; d < 16; ++d)
                s += qkv[i][h*16 + d] * qkv[k][EMBED + h*16 + d];
            s *= 0.25f;
            sc[k] = s;
            mx = fmaxf(mx, s);
        }
        float denom = 0.f;
        #pragma unroll
        for (int k = 0; k < QLEN; ++k) { sc[k] = expf(sc[k] - mx); denom += sc[k]; }
        float inv = 1.0f / denom;
        #pragma unroll
        for (int d = 0; d < 16; ++d) {
            float acc = 0.f;
            #pragma unroll
            for (int k = 0; k < QLEN; ++k)
                acc += sc[k] * qkv[k][2*EMBED + h*16 + d];
            ctx[i][h*16 + d] = acc * inv;
        }
    }
    __syncthreads();

    if (t < EMBED) {
        float acc = 0.f;
        #pragma unroll
        for (int q = 0; q < QLEN; ++q) acc += ctx[q][t];
        mctx[t] = acc * (1.0f/QLEN);
    }
    __syncthreads();

    if (t < EMBED) {
        float acc = bout[t];
        const float* wrow = &Wout[t*EMBED];
        #pragma unroll
        for (int d = 0; d < EMBED; ++d) acc += mctx[d] * wrow[d];
        qenc[b*EMBED + t] = acc;
    }
}

// ----------------------------------------------------------------- losses --
__device__ __forceinline__ float log_sigmoid(float x) {
    float l = log1pf(expf(-fabsf(x)));
    return x >= 0.f ? -l : x - l;
}
__device__ __forceinline__ float wred(float v) {
    #pragma unroll
    for (int off = 32; off; off >>= 1) v += __shfl_xor(v, off);
    return v;
}

__global__ void loss_kernel(const float* __restrict__ sel,
                            const float* __restrict__ qenc,
                            float* __restrict__ out) {
    int b = blockIdx.x;
    int d = threadIdx.x;   // 0..63
    const float scale = 0.25f;
    float u   = sel[(size_t)b*EMBED + d] * scale;
    float pos = sel[(size_t)(BATCH + b)*EMBED + d] * scale;
    float p   = qenc[b*EMBED + d] + 0.1f * u;

    float s_up = wred(u * pos);
    float s_pp = wred(p * pos);
    float nu[NNEG], np_[NNEG];
    #pragma unroll
    for (int n = 0; n < NNEG; ++n) {
        float ng = sel[(size_t)(2*BATCH + b*NNEG + n)*EMBED + d] * scale;
        nu[n]  = wred(u * ng);
        np_[n] = wred(p * ng);
    }
    if (d == 0) {
        float cf = 0.f, srch_neg = 0.f;
        #pragma unroll
        for (int n = 0; n < NNEG; ++n) {
            cf       += -log_sigmoid(s_up - nu[n]);
            srch_neg += -log_sigmoid(-np_[n]);
        }
        float res = cf * (1.0f/(BATCH*NNEG))
                  + (-log_sigmoid(s_pp)) * (1.0f/BATCH)
                  + srch_neg * (1.0f/(BATCH*NNEG));
        atomicAdd(out, res);
    }
}

// ---------------------------------------------------------------- launch ---
extern "C" void kernel_launch(void* const* d_in, const int* in_sizes, int n_in,
                              void* d_out, int out_size, void* d_ws, size_t ws_size,
                              hipStream_t stream) {
    const float* entity_w   = (const float*)d_in[0];
    const float* word_w     = (const float*)d_in[1];
    const float* in_proj_w  = (const float*)d_in[2];
    const float* in_proj_b  = (const float*)d_in[3];
    const float* out_proj_w = (const float*)d_in[4];
    const float* out_proj_b = (const float*)d_in[5];
    const float* edge_val   = (const float*)d_in[6];
    const int*   users      = (const int*)d_in[7];
    const int*   items      = (const int*)d_in[8];
    const int*   qwords     = (const int*)d_in[9];
    const int*   neg_items  = (const int*)d_in[10];
    const int*   edge_row   = (const int*)d_in[11];
    const int*   edge_col   = (const int*)d_in[12];
    float* out = (float*)d_out;

    const size_t HN = (size_t)N_ENTITY * EMBED;

    size_t need = sizeof(int2)  * (size_t)N_EDGES               // ebuf
                + sizeof(float) * HN * 2                        // hA, hB
                + sizeof(float) * (size_t)NSEL * EMBED          // sel
                + sizeof(float) * (size_t)BATCH * EMBED         // qenc
                + sizeof(int)   * (size_t)NBUCKET               // bucket_cnt
                + sizeof(int)   * (size_t)(NBUCKET + 1)         // bstart
                + sizeof(int)   * (size_t)NBLK_PART * NBUCKET   // blockBase
                + sizeof(unsigned int) * (size_t)BM_WORDS * 2;  // bmSel, bmNeed

    hipMemsetAsync(out, 0, sizeof(float) * out_size, stream);

    if (ws_size >= need) {
        int2*  ebuf = (int2*)d_ws;
        float* hA   = (float*)(ebuf + N_EDGES);
        float* hB   = hA + HN;
        float* sel  = hB + HN;
        float* qenc = sel + (size_t)NSEL * EMBED;
        int* bucket_cnt = (int*)(qenc + (size_t)BATCH * EMBED);
        int* bstart     = bucket_cnt + NBUCKET;
        int* blockBase  = bstart + NBUCKET + 1;
        unsigned int* bmSel  = (unsigned int*)(blockBase + (size_t)NBLK_PART * NBUCKET);
        unsigned int* bmNeed = bmSel + BM_WORDS;

        hipMemsetAsync(bucket_cnt, 0, sizeof(int) * NBUCKET, stream);
        hipMemsetAsync(bmSel,  0, sizeof(unsigned int) * BM_WORDS, stream);
        hipMemsetAsync(bmNeed, 0, sizeof(unsigned int) * BM_WORDS, stream);

        mark_sel_kernel<<<(NSEL + 255) / 256, 256, 0, stream>>>(
            users, items, neg_items, bmSel, bmNeed);

        part_hist_kernel<<<NBLK_PART, 256, 0, stream>>>(edge_row, bucket_cnt, blockBase);
        bucket_scan_kernel<<<1, 256, 0, stream>>>(bucket_cnt, bstart);
        part_scatter_kernel<<<NBLK_PART, 256, 0, stream>>>(
            edge_row, edge_col, edge_val, bstart, blockBase, bmSel, bmNeed, ebuf);

        // layer 0
        sel_accum_kernel<<<(NSEL * EMBED) / 256, 256, 0, stream>>>(
            entity_w, users, items, neg_items, sel, 1);

        // layer 1: full
        spmm_bucket_kernel<0><<<NBUCKET, 256, 0, stream>>>(
            entity_w, hA, bstart, ebuf, nullptr);
        sel_accum_kernel<<<(NSEL * EMBED) / 256, 256, 0, stream>>>(
            hA, users, items, neg_items, sel, 0);

        // layer 2: rows needed by layer-3 gathers (+ sel rows)
        spmm_bucket_kernel<1><<<NBUCKET, 256, 0, stream>>>(
            hA, hB, bstart, ebuf, bmNeed);
        sel_accum_kernel<<<(NSEL * EMBED) / 256, 256, 0, stream>>>(
            hB, users, items, neg_items, sel, 0);

        // layer 3: sel rows only
        spmm_bucket_kernel<1><<<NBUCKET, 256, 0, stream>>>(
            hB, hA, bstart, ebuf, bmSel);
        sel_accum_kernel<<<(NSEL * EMBED) / 256, 256, 0, stream>>>(
            hA, users, items, neg_items, sel, 0);

        sent_kernel<<<BATCH, 128, 0, stream>>>(qwords, word_w, in_proj_w, in_proj_b,
                                               out_proj_w, out_proj_b, qenc);
        loss_kernel<<<BATCH, 64, 0, stream>>>(sel, qenc, out);
    } else {
        // -------- fallback: atomic path (~105 MB ws) --------
        float* hA   = (float*)d_ws;
        float* hB   = hA + HN;
        float* sel  = hB + HN;
        float* qenc = sel + (size_t)NSEL * EMBED;
        unsigned int* bm = (unsigned int*)(qenc + (size_t)BATCH * EMBED);

        hipMemsetAsync(bm, 0, sizeof(unsigned int) * BM_WORDS, stream);
        bitmap_build_kernel<<<(NSEL + 255) / 256, 256, 0, stream>>>(users, items, neg_items, bm);
        sel_accum_kernel<<<(NSEL * EMBED) / 256, 256, 0, stream>>>(
            entity_w, users, items, neg_items, sel, 1);
        hipMemsetAsync(hA, 0, HN * sizeof(float), stream);
        spmm_kernel<<<2048, 256, 0, stream>>>(entity_w, hA, edge_row, edge_col, edge_val, N_EDGES);
        sel_accum_kernel<<<(NSEL * EMBED) / 256, 256, 0, stream>>>(
            hA, users, items, neg_items, sel, 0);
        hipMemsetAsync(hB, 0, HN * sizeof(float), stream);
        spmm_kernel<<<2048, 256, 0, stream>>>(hA, hB, edge_row, edge_col, edge_val, N_EDGES);
        sel_accum_kernel<<<(NSEL * EMBED) / 256, 256, 0, stream>>>(
            hB, users, items, neg_items, sel, 0);
        hipMemsetAsync(hA, 0, HN * sizeof(float), stream);
        spmm_filtered_kernel<<<2048, 256, 0, stream>>>(hB, hA, edge_row, edge_col, edge_val, bm, N_EDGES);
        sel_accum_kernel<<<(NSEL * EMBED) / 256, 256, 0, stream>>>(
            hA, users, items, neg_items, sel, 0);
        sent_kernel<<<BATCH, 128, 0, stream>>>(qwords, word_w, in_proj_w, in_proj_b,
                                               out_proj_w, out_proj_b, qenc);
        loss_kernel<<<BATCH, 64, 0, stream>>>(sel, qenc, out);
    }
}

// Round 4
// 869.519 us; speedup vs baseline: 5.3458x; 5.3458x over previous
//
#include <hip/hip_runtime.h>
#include <math.h>

#define N_ENTITY 200000
#define EMBED    64
#define N_EDGES  6400000
#define BATCH    1024
#define QLEN     20
#define NNEG     5
#define NSEL     (BATCH + BATCH + BATCH*NNEG)   // 7168 gathered rows
#define BM_WORDS ((N_ENTITY + 31) / 32)
#define COLMASK  0x3FFFF

#define BROWS     128                                // rows per bucket
#define NBUCKET   ((N_ENTITY + BROWS - 1) / BROWS)   // 1563
#define NBLK_PART 192

// ---------------------------------------------- sel helpers ---------------
__device__ __forceinline__ int sel_row(int i, const int* users, const int* items,
                                       const int* negs) {
    if (i < BATCH)        return users[i];
    if (i < 2 * BATCH)    return items[i - BATCH];
    return negs[i - 2 * BATCH];
}

// ------------------------------------------------------ edge partition ----
__global__ void part_hist_kernel(const int* __restrict__ erow,
                                 int* __restrict__ bucket_cnt,
                                 int* __restrict__ blockBase) {
    __shared__ int h[NBUCKET];
    int blk = blockIdx.x, t = threadIdx.x;
    for (int i = t; i < NBUCKET; i += 256) h[i] = 0;
    __syncthreads();
    int per = (N_EDGES + NBLK_PART - 1) / NBLK_PART;
    int s = blk * per, e = min(s + per, N_EDGES);
    for (int j = s + t; j < e; j += 256)
        atomicAdd(&h[erow[j] >> 7], 1);
    __syncthreads();
    for (int i = t; i < NBUCKET; i += 256)
        blockBase[blk * NBUCKET + i] = atomicAdd(&bucket_cnt[i], h[i]);
}

__global__ void bucket_scan_kernel(const int* __restrict__ cnt,
                                   int* __restrict__ bstart) {
    __shared__ int s[256];
    int t = threadIdx.x;
    int loc[7];
    int sum = 0;
    #pragma unroll
    for (int k = 0; k < 7; ++k) {
        int i = t * 7 + k;
        int c = (i < NBUCKET) ? cnt[i] : 0;
        loc[k] = sum; sum += c;
    }
    s[t] = sum; __syncthreads();
    for (int off = 1; off < 256; off <<= 1) {
        int x = (t >= off) ? s[t - off] : 0;
        __syncthreads();
        s[t] += x;
        __syncthreads();
    }
    int excl = t ? s[t - 1] : 0;
    #pragma unroll
    for (int k = 0; k < 7; ++k) {
        int i = t * 7 + k;
        if (i < NBUCKET) bstart[i] = excl + loc[k];
    }
    if (t == 255) bstart[NBUCKET] = excl + sum;   // = N_EDGES
}

__global__ void part_scatter_kernel(const int* __restrict__ erow,
                                    const int* __restrict__ ecol,
                                    const float* __restrict__ evalv,
                                    const int* __restrict__ bstart,
                                    const int* __restrict__ blockBase,
                                    int2* __restrict__ ebuf) {
    __shared__ int cur[NBUCKET];
    int blk = blockIdx.x, t = threadIdx.x;
    for (int i = t; i < NBUCKET; i += 256)
        cur[i] = bstart[i] + blockBase[blk * NBUCKET + i];
    __syncthreads();
    int per = (N_EDGES + NBLK_PART - 1) / NBLK_PART;
    int s = blk * per, e = min(s + per, N_EDGES);
    for (int j = s + t; j < e; j += 256) {
        int   r = erow[j];
        int   c = ecol[j];
        float v = evalv[j];
        int pos = atomicAdd(&cur[r >> 7], 1);            // LDS atomic
        ebuf[pos] = make_int2(c | ((r & 127) << 18), __float_as_int(v));
    }
}

// --------------------------- bucket-local counting sort -> exact CSR ------
__global__ void bucket_sort_kernel(const int2* __restrict__ ebuf,
                                   const int* __restrict__ bstart,
                                   int2* __restrict__ ebuf2,
                                   int* __restrict__ rowptr) {
    __shared__ int hist[BROWS];
    __shared__ int cur[BROWS];
    int b = blockIdx.x, t = threadIdx.x;
    int beg = bstart[b], end = bstart[b + 1];
    if (t < BROWS) hist[t] = 0;
    __syncthreads();
    for (int j = beg + t; j < end; j += 256)
        atomicAdd(&hist[ebuf[j].x >> 18], 1);
    __syncthreads();
    if (t < BROWS) cur[t] = hist[t];
    __syncthreads();
    for (int off = 1; off < BROWS; off <<= 1) {
        int x = 0;
        if (t < BROWS && t >= off) x = cur[t - off];
        __syncthreads();
        if (t < BROWS && t >= off) cur[t] += x;
        __syncthreads();
    }
    int excl = 0;
    if (t < BROWS) excl = t ? cur[t - 1] : 0;
    __syncthreads();
    if (t < BROWS) {
        int r = (b << 7) + t;
        if (r <= N_ENTITY) rowptr[r] = beg + excl;
        cur[t] = beg + excl;
    }
    __syncthreads();
    for (int j = beg + t; j < end; j += 256) {
        int2 e = ebuf[j];
        int pos = atomicAdd(&cur[e.x >> 18], 1);         // LDS atomic
        ebuf2[pos] = e;
    }
}

// ---------------------- needed-rows bitmap (sel rows + their neighbors) ---
__global__ void need_build_kernel(const int* __restrict__ users,
                                  const int* __restrict__ items,
                                  const int* __restrict__ negs,
                                  const int* __restrict__ rowptr,
                                  const int2* __restrict__ edges,
                                  unsigned int* __restrict__ bm) {
    int lane = threadIdx.x & 63;
    int wave = blockIdx.x * (blockDim.x >> 6) + (threadIdx.x >> 6);
    if (wave >= NSEL) return;
    int idx = sel_row(wave, users, items, negs);
    if (lane == 0) atomicOr(&bm[idx >> 5], 1u << (idx & 31));
    int beg = rowptr[idx], end = rowptr[idx + 1];
    for (int j = beg + lane; j < end; j += 64) {
        int c = edges[j].x & COLMASK;
        atomicOr(&bm[c >> 5], 1u << (c & 31));
    }
}

// -------------------------------------------------------------- CSR SpMM ---
template<int FILTER>
__global__ void spmm_csr_kernel(const float* __restrict__ src, float* __restrict__ dst,
                                const int* __restrict__ rowptr,
                                const int2* __restrict__ edges,
                                const unsigned int* __restrict__ bm) {
    int lane  = threadIdx.x & 63;
    int wave  = blockIdx.x * (blockDim.x >> 6) + (threadIdx.x >> 6);
    int nwave = gridDim.x * (blockDim.x >> 6);
    for (int row = wave; row < N_ENTITY; row += nwave) {
        if (FILTER && !((bm[row >> 5] >> (row & 31)) & 1u)) continue;
        int beg = rowptr[row], end = rowptr[row + 1];
        float acc = 0.f;
        int j = beg;
        for (; j + 4 <= end; j += 4) {
            int2 e0 = edges[j], e1 = edges[j+1], e2 = edges[j+2], e3 = edges[j+3];
            float x0 = src[(size_t)(e0.x & COLMASK) * EMBED + lane];
            float x1 = src[(size_t)(e1.x & COLMASK) * EMBED + lane];
            float x2 = src[(size_t)(e2.x & COLMASK) * EMBED + lane];
            float x3 = src[(size_t)(e3.x & COLMASK) * EMBED + lane];
            acc += __int_as_float(e0.y) * x0;
            acc += __int_as_float(e1.y) * x1;
            acc += __int_as_float(e2.y) * x2;
            acc += __int_as_float(e3.y) * x3;
        }
        for (; j < end; ++j) {
            int2 e = edges[j];
            acc += __int_as_float(e.y) * src[(size_t)(e.x & COLMASK) * EMBED + lane];
        }
        dst[(size_t)row * EMBED + lane] = acc;
    }
}

// layer-3 direct pull: sel[i] += sum_j val * h2[col]
__global__ void sel_pull_kernel(const float* __restrict__ h,
                                const int* __restrict__ users,
                                const int* __restrict__ items,
                                const int* __restrict__ negs,
                                const int* __restrict__ rowptr,
                                const int2* __restrict__ edges,
                                float* __restrict__ sel) {
    int lane = threadIdx.x & 63;
    int wave = blockIdx.x * (blockDim.x >> 6) + (threadIdx.x >> 6);
    if (wave >= NSEL) return;
    int idx = sel_row(wave, users, items, negs);
    int beg = rowptr[idx], end = rowptr[idx + 1];
    float acc = 0.f;
    int j = beg;
    for (; j + 2 <= end; j += 2) {
        int2 e0 = edges[j], e1 = edges[j+1];
        acc += __int_as_float(e0.y) * h[(size_t)(e0.x & COLMASK) * EMBED + lane];
        acc += __int_as_float(e1.y) * h[(size_t)(e1.x & COLMASK) * EMBED + lane];
    }
    for (; j < end; ++j) {
        int2 e = edges[j];
        acc += __int_as_float(e.y) * h[(size_t)(e.x & COLMASK) * EMBED + lane];
    }
    sel[(size_t)wave * EMBED + lane] += acc;
}

// ------------------------------------------------- sel accumulate ---------
__global__ void sel_accum_kernel(const float* __restrict__ h,
                                 const int* __restrict__ users,
                                 const int* __restrict__ items,
                                 const int* __restrict__ negs,
                                 float* __restrict__ sel, int init) {
    int tid = blockIdx.x * blockDim.x + threadIdx.x;
    if (tid >= NSEL * EMBED) return;
    int i = tid >> 6, d = tid & 63;
    int idx = sel_row(i, users, items, negs);
    float v = h[(size_t)idx * EMBED + d];
    if (init) sel[tid] = v;
    else      sel[tid] += v;
}

// --------------------------------------- fallback (atomic) path -----------
__global__ void spmm_kernel(const float* __restrict__ src, float* __restrict__ dst,
                            const int* __restrict__ erow, const int* __restrict__ ecol,
                            const float* __restrict__ evalv, int n_edges) {
    int lane  = threadIdx.x & 63;
    int wave  = blockIdx.x * (blockDim.x >> 6) + (threadIdx.x >> 6);
    int nwave = gridDim.x * (blockDim.x >> 6);
    for (int e = wave; e < n_edges; e += nwave) {
        int   r = erow[e];
        int   c = ecol[e];
        float v = evalv[e];
        float x = src[(size_t)c * EMBED + lane];
        atomicAdd(&dst[(size_t)r * EMBED + lane], v * x);
    }
}

__global__ void spmm_filtered_kernel(const float* __restrict__ src, float* __restrict__ dst,
                                     const int* __restrict__ erow, const int* __restrict__ ecol,
                                     const float* __restrict__ evalv,
                                     const unsigned int* __restrict__ bm, int n_edges) {
    int lane  = threadIdx.x & 63;
    int wave  = blockIdx.x * (blockDim.x >> 6) + (threadIdx.x >> 6);
    int nwave = gridDim.x * (blockDim.x >> 6);
    for (int e = wave; e < n_edges; e += nwave) {
        int r = erow[e];
        if (!((bm[r >> 5] >> (r & 31)) & 1u)) continue;
        int   c = ecol[e];
        float v = evalv[e];
        float x = src[(size_t)c * EMBED + lane];
        atomicAdd(&dst[(size_t)r * EMBED + lane], v * x);
    }
}

__global__ void bitmap_build_kernel(const int* __restrict__ users,
                                    const int* __restrict__ items,
                                    const int* __restrict__ negs,
                                    unsigned int* __restrict__ bm) {
    int i = blockIdx.x * blockDim.x + threadIdx.x;
    if (i >= NSEL) return;
    int idx = sel_row(i, users, items, negs);
    atomicOr(&bm[idx >> 5], 1u << (idx & 31));
}

// -------------------------------------------------------- sentence encode --
__global__ void sent_kernel(const int* __restrict__ qwords,
                            const float* __restrict__ word_w,
                            const float* __restrict__ Win,  const float* __restrict__ bin,
                            const float* __restrict__ Wout, const float* __restrict__ bout,
                            float* __restrict__ qenc) {
    __shared__ float x[QLEN][EMBED];
    __shared__ float qkv[QLEN][3*EMBED];
    __shared__ float ctx[QLEN][EMBED];
    __shared__ float mctx[EMBED];
    int b = blockIdx.x;
    int t = threadIdx.x;   // 0..127

    for (int j = t; j < QLEN*EMBED; j += 128) {
        int q = j >> 6, d = j & 63;
        int w = qwords[b*QLEN + q];
        x[q][d] = word_w[(size_t)w * EMBED + d];
    }
    __syncthreads();

    for (int j = t; j < QLEN*192; j += 128) {
        int q = j / 192, o = j % 192;
        float acc = bin[o];
        const float* wrow = &Win[o*EMBED];
        #pragma unroll
        for (int d = 0; d < EMBED; ++d) acc += x[q][d] * wrow[d];
        qkv[q][o] = acc;
    }
    __syncthreads();

    if (t < 4*QLEN) {
        int h = t / QLEN, i = t % QLEN;
        float sc[QLEN];
        float mx = -1e30f;
        #pragma unroll
        for (int k = 0; k < QLEN; ++k) {
            float s = 0.f;
            #pragma unroll
            for (int d = 0; d < 16; ++d)
                s += qkv[i][h*16 + d] * qkv[k][EMBED + h*16 + d];
            s *= 0.25f;
            sc[k] = s;
            mx = fmaxf(mx, s);
        }
        float denom = 0.f;
        #pragma unroll
        for (int k = 0; k < QLEN; ++k) { sc[k] = expf(sc[k] - mx); denom += sc[k]; }
        float inv = 1.0f / denom;
        #pragma unroll
        for (int d = 0; d < 16; ++d) {
            float acc = 0.f;
            #pragma unroll
            for (int k = 0; k < QLEN; ++k)
                acc += sc[k] * qkv[k][2*EMBED + h*16 + d];
            ctx[i][h*16 + d] = acc * inv;
        }
    }
    __syncthreads();

    if (t < EMBED) {
        float acc = 0.f;
        #pragma unroll
        for (int q = 0; q < QLEN; ++q) acc += ctx[q][t];
        mctx[t] = acc * (1.0f/QLEN);
    }
    __syncthreads();

    if (t < EMBED) {
        float acc = bout[t];
        const float* wrow = &Wout[t*EMBED];
        #pragma unroll
        for (int d = 0; d < EMBED; ++d) acc += mctx[d] * wrow[d];
        qenc[b*EMBED + t] = acc;
    }
}

// ----------------------------------------------------------------- losses --
__device__ __forceinline__ float log_sigmoid(float x) {
    float l = log1pf(expf(-fabsf(x)));
    return x >= 0.f ? -l : x - l;
}
__device__ __forceinline__ float wred(float v) {
    #pragma unroll
    for (int off = 32; off; off >>= 1) v += __shfl_xor(v, off);
    return v;
}

__global__ void loss_kernel(const float* __restrict__ sel,
                            const float* __restrict__ qenc,
                            float* __restrict__ out) {
    int b = blockIdx.x;
    int d = threadIdx.x;   // 0..63
    const float scale = 0.25f;
    float u   = sel[(size_t)b*EMBED + d] * scale;
    float pos = sel[(size_t)(BATCH + b)*EMBED + d] * scale;
    float p   = qenc[b*EMBED + d] + 0.1f * u;

    float s_up = wred(u * pos);
    float s_pp = wred(p * pos);
    float nu[NNEG], np_[NNEG];
    #pragma unroll
    for (int n = 0; n < NNEG; ++n) {
        float ng = sel[(size_t)(2*BATCH + b*NNEG + n)*EMBED + d] * scale;
        nu[n]  = wred(u * ng);
        np_[n] = wred(p * ng);
    }
    if (d == 0) {
        float cf = 0.f, srch_neg = 0.f;
        #pragma unroll
        for (int n = 0; n < NNEG; ++n) {
            cf       += -log_sigmoid(s_up - nu[n]);
            srch_neg += -log_sigmoid(-np_[n]);
        }
        float res = cf * (1.0f/(BATCH*NNEG))
                  + (-log_sigmoid(s_pp)) * (1.0f/BATCH)
                  + srch_neg * (1.0f/(BATCH*NNEG));
        atomicAdd(out, res);
    }
}

// ---------------------------------------------------------------- launch ---
extern "C" void kernel_launch(void* const* d_in, const int* in_sizes, int n_in,
                              void* d_out, int out_size, void* d_ws, size_t ws_size,
                              hipStream_t stream) {
    const float* entity_w   = (const float*)d_in[0];
    const float* word_w     = (const float*)d_in[1];
    const float* in_proj_w  = (const float*)d_in[2];
    const float* in_proj_b  = (const float*)d_in[3];
    const float* out_proj_w = (const float*)d_in[4];
    const float* out_proj_b = (const float*)d_in[5];
    const float* edge_val   = (const float*)d_in[6];
    const int*   users      = (const int*)d_in[7];
    const int*   items      = (const int*)d_in[8];
    const int*   qwords     = (const int*)d_in[9];
    const int*   neg_items  = (const int*)d_in[10];
    const int*   edge_row   = (const int*)d_in[11];
    const int*   edge_col   = (const int*)d_in[12];
    float* out = (float*)d_out;

    const size_t HN = (size_t)N_ENTITY * EMBED;   // 12.8M floats = 51.2 MB

    // Layout: ebuf2 | ebuf(=hA after sort) | hB(build scratch inside) |
    //         sel | qenc | rowptr | bmNeed      -> ~156.7 MB
    size_t need = sizeof(int2)  * (size_t)N_EDGES * 2          // ebuf2 + ebuf/hA
                + sizeof(float) * HN                           // hB
                + sizeof(float) * (size_t)NSEL * EMBED         // sel
                + sizeof(float) * (size_t)BATCH * EMBED        // qenc
                + sizeof(int)   * (size_t)(N_ENTITY + 1)       // rowptr
                + sizeof(unsigned int) * (size_t)BM_WORDS;     // bmNeed

    hipMemsetAsync(out, 0, sizeof(float) * out_size, stream);

    if (ws_size >= need) {
        int2*  ebuf2 = (int2*)d_ws;
        int2*  ebuf  = ebuf2 + N_EDGES;
        float* hA    = (float*)ebuf;                 // alias: ebuf dead after sort
        float* hB    = (float*)(ebuf + N_EDGES);
        float* sel   = hB + HN;
        float* qenc  = sel + (size_t)NSEL * EMBED;
        int*   rowptr = (int*)(qenc + (size_t)BATCH * EMBED);
        unsigned int* bmNeed = (unsigned int*)(rowptr + N_ENTITY + 1);
        // build-time scratch overlaid on hB (dead until layer-2 write)
        int* bucket_cnt = (int*)hB;
        int* bstart     = bucket_cnt + NBUCKET;
        int* blockBase  = bstart + NBUCKET + 1;      // 192*1563 ints ~1.2MB << 51.2MB

        hipMemsetAsync(bucket_cnt, 0, sizeof(int) * NBUCKET, stream);
        hipMemsetAsync(bmNeed, 0, sizeof(unsigned int) * BM_WORDS, stream);

        // --- atomic-free CSR build ---
        part_hist_kernel<<<NBLK_PART, 256, 0, stream>>>(edge_row, bucket_cnt, blockBase);
        bucket_scan_kernel<<<1, 256, 0, stream>>>(bucket_cnt, bstart);
        part_scatter_kernel<<<NBLK_PART, 256, 0, stream>>>(
            edge_row, edge_col, edge_val, bstart, blockBase, ebuf);
        bucket_sort_kernel<<<NBUCKET, 256, 0, stream>>>(ebuf, bstart, ebuf2, rowptr);

        // --- needed-rows bitmap (sel + neighbors of sel) ---
        need_build_kernel<<<(NSEL + 3) / 4, 256, 0, stream>>>(
            users, items, neg_items, rowptr, ebuf2, bmNeed);

        // --- layer 0 ---
        sel_accum_kernel<<<(NSEL * EMBED) / 256, 256, 0, stream>>>(
            entity_w, users, items, neg_items, sel, 1);

        // --- layer 1: full (hA aliases ebuf, which is dead now) ---
        spmm_csr_kernel<0><<<2048, 256, 0, stream>>>(entity_w, hA, rowptr, ebuf2, nullptr);
        sel_accum_kernel<<<(NSEL * EMBED) / 256, 256, 0, stream>>>(
            hA, users, items, neg_items, sel, 0);

        // --- layer 2: only rows needed downstream (build scratch in hB dead) ---
        spmm_csr_kernel<1><<<2048, 256, 0, stream>>>(hA, hB, rowptr, ebuf2, bmNeed);
        sel_accum_kernel<<<(NSEL * EMBED) / 256, 256, 0, stream>>>(
            hB, users, items, neg_items, sel, 0);

        // --- layer 3: direct pull into sel ---
        sel_pull_kernel<<<(NSEL + 3) / 4, 256, 0, stream>>>(
            hB, users, items, neg_items, rowptr, ebuf2, sel);

        sent_kernel<<<BATCH, 128, 0, stream>>>(qwords, word_w, in_proj_w, in_proj_b,
                                               out_proj_w, out_proj_b, qenc);
        loss_kernel<<<BATCH, 64, 0, stream>>>(sel, qenc, out);
    } else {
        // -------- fallback: atomic path (~105 MB ws) --------
        float* hA   = (float*)d_ws;
        float* hB   = hA + HN;
        float* sel  = hB + HN;
        float* qenc = sel + (size_t)NSEL * EMBED;
        unsigned int* bm = (unsigned int*)(qenc + (size_t)BATCH * EMBED);

        hipMemsetAsync(bm, 0, sizeof(unsigned int) * BM_WORDS, stream);
        bitmap_build_kernel<<<(NSEL + 255) / 256, 256, 0, stream>>>(users, items, neg_items, bm);
        sel_accum_kernel<<<(NSEL * EMBED) / 256, 256, 0, stream>>>(
            entity_w, users, items, neg_items, sel, 1);
        hipMemsetAsync(hA, 0, HN * sizeof(float), stream);
        spmm_kernel<<<2048, 256, 0, stream>>>(entity_w, hA, edge_row, edge_col, edge_val, N_EDGES);
        sel_accum_kernel<<<(NSEL * EMBED) / 256, 256, 0, stream>>>(
            hA, users, items, neg_items, sel, 0);
        hipMemsetAsync(hB, 0, HN * sizeof(float), stream);
        spmm_kernel<<<2048, 256, 0, stream>>>(hA, hB, edge_row, edge_col, edge_val, N_EDGES);
        sel_accum_kernel<<<(NSEL * EMBED) / 256, 256, 0, stream>>>(
            hB, users, items, neg_items, sel, 0);
        hipMemsetAsync(hA, 0, HN * sizeof(float), stream);
        spmm_filtered_kernel<<<2048, 256, 0, stream>>>(hB, hA, edge_row, edge_col, edge_val, bm, N_EDGES);
        sel_accum_kernel<<<(NSEL * EMBED) / 256, 256, 0, stream>>>(
            hA, users, items, neg_items, sel, 0);
        sent_kernel<<<BATCH, 128, 0, stream>>>(qwords, word_w, in_proj_w, in_proj_b,
                                               out_proj_w, out_proj_b, qenc);
        loss_kernel<<<BATCH, 64, 0, stream>>>(sel, qenc, out);
    }
}

// Round 5
// 852.543 us; speedup vs baseline: 5.4523x; 1.0199x over previous
//
#include <hip/hip_runtime.h>
#include <math.h>

#define N_ENTITY 200000
#define EMBED    64
#define N_EDGES  6400000
#define BATCH    1024
#define QLEN     20
#define NNEG     5
#define NSEL     (BATCH + BATCH + BATCH*NNEG)   // 7168 gathered rows
#define BM_WORDS ((N_ENTITY + 31) / 32)
#define COLMASK  0x3FFFF

#define BROWS     128                                // rows per bucket
#define NBUCKET   ((N_ENTITY + BROWS - 1) / BROWS)   // 1563
#define NBLK_PART 192

typedef unsigned int   uint32;
typedef unsigned short ushort16;

__device__ __forceinline__ ushort16 f2bf(float f) {
    uint32 b = __float_as_uint(f);
    uint32 r = (b + 0x7FFFu + ((b >> 16) & 1u)) >> 16;   // RNE
    return (ushort16)r;
}
__device__ __forceinline__ float bf2f(ushort16 h) {
    return __uint_as_float(((uint32)h) << 16);
}

// ---------------------------------------------- sel helpers ---------------
__device__ __forceinline__ int sel_row(int i, const int* users, const int* items,
                                       const int* negs) {
    if (i < BATCH)        return users[i];
    if (i < 2 * BATCH)    return items[i - BATCH];
    return negs[i - 2 * BATCH];
}

// ------------------------------------------------------ edge partition ----
__global__ void part_hist_kernel(const int* __restrict__ erow,
                                 int* __restrict__ bucket_cnt,
                                 int* __restrict__ blockBase) {
    __shared__ int h[NBUCKET];
    int blk = blockIdx.x, t = threadIdx.x;
    for (int i = t; i < NBUCKET; i += 256) h[i] = 0;
    __syncthreads();
    int per = (N_EDGES + NBLK_PART - 1) / NBLK_PART;
    int s = blk * per, e = min(s + per, N_EDGES);
    for (int j = s + t; j < e; j += 256)
        atomicAdd(&h[erow[j] >> 7], 1);
    __syncthreads();
    for (int i = t; i < NBUCKET; i += 256)
        blockBase[blk * NBUCKET + i] = atomicAdd(&bucket_cnt[i], h[i]);
}

__global__ void bucket_scan_kernel(const int* __restrict__ cnt,
                                   int* __restrict__ bstart) {
    __shared__ int s[256];
    int t = threadIdx.x;
    int loc[7];
    int sum = 0;
    #pragma unroll
    for (int k = 0; k < 7; ++k) {
        int i = t * 7 + k;
        int c = (i < NBUCKET) ? cnt[i] : 0;
        loc[k] = sum; sum += c;
    }
    s[t] = sum; __syncthreads();
    for (int off = 1; off < 256; off <<= 1) {
        int x = (t >= off) ? s[t - off] : 0;
        __syncthreads();
        s[t] += x;
        __syncthreads();
    }
    int excl = t ? s[t - 1] : 0;
    #pragma unroll
    for (int k = 0; k < 7; ++k) {
        int i = t * 7 + k;
        if (i < NBUCKET) bstart[i] = excl + loc[k];
    }
    if (t == 255) bstart[NBUCKET] = excl + sum;   // = N_EDGES
}

// scatter into bucket-grouped (colrow int, val bf16) arrays
__global__ void part_scatter_kernel(const int* __restrict__ erow,
                                    const int* __restrict__ ecol,
                                    const float* __restrict__ evalv,
                                    const int* __restrict__ bstart,
                                    const int* __restrict__ blockBase,
                                    int* __restrict__ ebuf_cr,
                                    ushort16* __restrict__ ebuf_v) {
    __shared__ int cur[NBUCKET];
    int blk = blockIdx.x, t = threadIdx.x;
    for (int i = t; i < NBUCKET; i += 256)
        cur[i] = bstart[i] + blockBase[blk * NBUCKET + i];
    __syncthreads();
    int per = (N_EDGES + NBLK_PART - 1) / NBLK_PART;
    int s = blk * per, e = min(s + per, N_EDGES);
    for (int j = s + t; j < e; j += 256) {
        int   r = erow[j];
        int   c = ecol[j];
        float v = evalv[j];
        int pos = atomicAdd(&cur[r >> 7], 1);            // LDS atomic
        ebuf_cr[pos] = c | ((r & 127) << 18);
        ebuf_v[pos]  = f2bf(v);
    }
}

// --------------------------- bucket-local counting sort -> exact CSR ------
__global__ void bucket_sort_kernel(const int* __restrict__ ebuf_cr,
                                   const ushort16* __restrict__ ebuf_v,
                                   const int* __restrict__ bstart,
                                   int* __restrict__ cols2,
                                   ushort16* __restrict__ vals2,
                                   int* __restrict__ rowptr) {
    __shared__ int hist[BROWS];
    __shared__ int cur[BROWS];
    int b = blockIdx.x, t = threadIdx.x;
    int beg = bstart[b], end = bstart[b + 1];
    if (t < BROWS) hist[t] = 0;
    __syncthreads();
    for (int j = beg + t; j < end; j += 256)
        atomicAdd(&hist[((unsigned)ebuf_cr[j]) >> 18], 1);
    __syncthreads();
    if (t < BROWS) cur[t] = hist[t];
    __syncthreads();
    for (int off = 1; off < BROWS; off <<= 1) {
        int x = 0;
        if (t < BROWS && t >= off) x = cur[t - off];
        __syncthreads();
        if (t < BROWS && t >= off) cur[t] += x;
        __syncthreads();
    }
    int excl = 0;
    if (t < BROWS) excl = t ? cur[t - 1] : 0;
    __syncthreads();
    if (t < BROWS) {
        int r = (b << 7) + t;
        if (r <= N_ENTITY) rowptr[r] = beg + excl;
        cur[t] = beg + excl;
    }
    __syncthreads();
    for (int j = beg + t; j < end; j += 256) {
        int cr = ebuf_cr[j];
        int pos = atomicAdd(&cur[((unsigned)cr) >> 18], 1);   // LDS atomic
        cols2[pos] = cr & COLMASK;
        vals2[pos] = ebuf_v[j];
    }
}

// ---------------------- needed-rows bitmap (sel rows + their neighbors) ---
__global__ void need_build_kernel(const int* __restrict__ users,
                                  const int* __restrict__ items,
                                  const int* __restrict__ negs,
                                  const int* __restrict__ rowptr,
                                  const int* __restrict__ cols2,
                                  unsigned int* __restrict__ bm) {
    int lane = threadIdx.x & 63;
    int wave = blockIdx.x * (blockDim.x >> 6) + (threadIdx.x >> 6);
    if (wave >= NSEL) return;
    int idx = sel_row(wave, users, items, negs);
    if (lane == 0) atomicOr(&bm[idx >> 5], 1u << (idx & 31));
    int beg = rowptr[idx], end = rowptr[idx + 1];
    for (int j = beg + lane; j < end; j += 64) {
        int c = cols2[j];
        atomicOr(&bm[c >> 5], 1u << (c & 31));
    }
}

// ----------------------------------------------- entity -> bf16 convert ---
__global__ void conv_bf16_kernel(const float* __restrict__ src,
                                 ushort16* __restrict__ dst) {
    int i = (blockIdx.x * blockDim.x + threadIdx.x) * 4;
    if (i >= N_ENTITY * EMBED) return;
    float4 v = *(const float4*)&src[i];
    uint32 p0 = (uint32)f2bf(v.x) | ((uint32)f2bf(v.y) << 16);
    uint32 p1 = (uint32)f2bf(v.z) | ((uint32)f2bf(v.w) << 16);
    *(uint2*)&dst[i] = make_uint2(p0, p1);
}

// --------------------------------------------------- bf16 CSR SpMM --------
// 2 edges per wave: half = lane>>5 picks edge parity, lane&31 = dim-pair.
template<int FILTER>
__global__ void spmm_bf16_kernel(const ushort16* __restrict__ src,
                                 ushort16* __restrict__ dst,
                                 const int* __restrict__ rowptr,
                                 const int* __restrict__ cols,
                                 const ushort16* __restrict__ vals,
                                 const unsigned int* __restrict__ bm) {
    int lane = threadIdx.x & 63;
    int half = lane >> 5;
    int l2   = lane & 31;
    int wave  = blockIdx.x * (blockDim.x >> 6) + (threadIdx.x >> 6);
    int nwave = gridDim.x * (blockDim.x >> 6);
    for (int row = wave; row < N_ENTITY; row += nwave) {
        if (FILTER && !((bm[row >> 5] >> (row & 31)) & 1u)) continue;
        int beg = rowptr[row], end = rowptr[row + 1];
        float ax = 0.f, ay = 0.f;
        int j = beg + half;
        for (; j + 2 < end; j += 4) {            // 2 edges per half per iter
            int   c0 = cols[j],     c1 = cols[j + 2];
            float v0 = bf2f(vals[j]);
            float v1 = bf2f(vals[j + 2]);
            uint32 p0 = *(const uint32*)&src[(size_t)c0 * EMBED + l2 * 2];
            uint32 p1 = *(const uint32*)&src[(size_t)c1 * EMBED + l2 * 2];
            ax += v0 * __uint_as_float(p0 << 16);
            ay += v0 * __uint_as_float(p0 & 0xFFFF0000u);
            ax += v1 * __uint_as_float(p1 << 16);
            ay += v1 * __uint_as_float(p1 & 0xFFFF0000u);
        }
        for (; j < end; j += 2) {
            int   c = cols[j];
            float v = bf2f(vals[j]);
            uint32 p = *(const uint32*)&src[(size_t)c * EMBED + l2 * 2];
            ax += v * __uint_as_float(p << 16);
            ay += v * __uint_as_float(p & 0xFFFF0000u);
        }
        ax += __shfl_xor(ax, 32);
        ay += __shfl_xor(ay, 32);
        if (half == 0) {
            uint32 packed = (uint32)f2bf(ax) | ((uint32)f2bf(ay) << 16);
            *(uint32*)&dst[(size_t)row * EMBED + l2 * 2] = packed;
        }
    }
}

// layer-3 direct pull: sel[i] += sum_j val * h2[col]   (h2 bf16)
__global__ void sel_pull_kernel(const ushort16* __restrict__ h,
                                const int* __restrict__ users,
                                const int* __restrict__ items,
                                const int* __restrict__ negs,
                                const int* __restrict__ rowptr,
                                const int* __restrict__ cols,
                                const ushort16* __restrict__ vals,
                                float* __restrict__ sel) {
    int lane = threadIdx.x & 63;
    int wave = blockIdx.x * (blockDim.x >> 6) + (threadIdx.x >> 6);
    if (wave >= NSEL) return;
    int idx = sel_row(wave, users, items, negs);
    int beg = rowptr[idx], end = rowptr[idx + 1];
    float acc = 0.f;
    int j = beg;
    for (; j + 2 <= end; j += 2) {
        int   c0 = cols[j], c1 = cols[j + 1];
        float v0 = bf2f(vals[j]), v1 = bf2f(vals[j + 1]);
        acc += v0 * bf2f(h[(size_t)c0 * EMBED + lane]);
        acc += v1 * bf2f(h[(size_t)c1 * EMBED + lane]);
    }
    for (; j < end; ++j)
        acc += bf2f(vals[j]) * bf2f(h[(size_t)cols[j] * EMBED + lane]);
    sel[(size_t)wave * EMBED + lane] += acc;
}

// ------------------------------------------------- sel accumulate ---------
__global__ void sel_init_kernel(const float* __restrict__ h,
                                const int* __restrict__ users,
                                const int* __restrict__ items,
                                const int* __restrict__ negs,
                                float* __restrict__ sel) {
    int tid = blockIdx.x * blockDim.x + threadIdx.x;
    if (tid >= NSEL * EMBED) return;
    int i = tid >> 6, d = tid & 63;
    int idx = sel_row(i, users, items, negs);
    sel[tid] = h[(size_t)idx * EMBED + d];
}

__global__ void sel_add_bf16_kernel(const ushort16* __restrict__ h,
                                    const int* __restrict__ users,
                                    const int* __restrict__ items,
                                    const int* __restrict__ negs,
                                    float* __restrict__ sel) {
    int tid = blockIdx.x * blockDim.x + threadIdx.x;
    if (tid >= NSEL * EMBED) return;
    int i = tid >> 6, d = tid & 63;
    int idx = sel_row(i, users, items, negs);
    sel[tid] += bf2f(h[(size_t)idx * EMBED + d]);
}

// --------------------------------------- fallback (atomic) path -----------
__global__ void spmm_kernel(const float* __restrict__ src, float* __restrict__ dst,
                            const int* __restrict__ erow, const int* __restrict__ ecol,
                            const float* __restrict__ evalv, int n_edges) {
    int lane  = threadIdx.x & 63;
    int wave  = blockIdx.x * (blockDim.x >> 6) + (threadIdx.x >> 6);
    int nwave = gridDim.x * (blockDim.x >> 6);
    for (int e = wave; e < n_edges; e += nwave) {
        int   r = erow[e];
        int   c = ecol[e];
        float v = evalv[e];
        float x = src[(size_t)c * EMBED + lane];
        atomicAdd(&dst[(size_t)r * EMBED + lane], v * x);
    }
}

__global__ void spmm_filtered_kernel(const float* __restrict__ src, float* __restrict__ dst,
                                     const int* __restrict__ erow, const int* __restrict__ ecol,
                                     const float* __restrict__ evalv,
                                     const unsigned int* __restrict__ bm, int n_edges) {
    int lane  = threadIdx.x & 63;
    int wave  = blockIdx.x * (blockDim.x >> 6) + (threadIdx.x >> 6);
    int nwave = gridDim.x * (blockDim.x >> 6);
    for (int e = wave; e < n_edges; e += nwave) {
        int r = erow[e];
        if (!((bm[r >> 5] >> (r & 31)) & 1u)) continue;
        int   c = ecol[e];
        float v = evalv[e];
        float x = src[(size_t)c * EMBED + lane];
        atomicAdd(&dst[(size_t)r * EMBED + lane], v * x);
    }
}

__global__ void bitmap_build_kernel(const int* __restrict__ users,
                                    const int* __restrict__ items,
                                    const int* __restrict__ negs,
                                    unsigned int* __restrict__ bm) {
    int i = blockIdx.x * blockDim.x + threadIdx.x;
    if (i >= NSEL) return;
    int idx = sel_row(i, users, items, negs);
    atomicOr(&bm[idx >> 5], 1u << (idx & 31));
}

__global__ void sel_accum_kernel(const float* __restrict__ h,
                                 const int* __restrict__ users,
                                 const int* __restrict__ items,
                                 const int* __restrict__ negs,
                                 float* __restrict__ sel, int init) {
    int tid = blockIdx.x * blockDim.x + threadIdx.x;
    if (tid >= NSEL * EMBED) return;
    int i = tid >> 6, d = tid & 63;
    int idx = sel_row(i, users, items, negs);
    float v = h[(size_t)idx * EMBED + d];
    if (init) sel[tid] = v;
    else      sel[tid] += v;
}

// -------------------------------------------------------- sentence encode --
__global__ void sent_kernel(const int* __restrict__ qwords,
                            const float* __restrict__ word_w,
                            const float* __restrict__ Win,  const float* __restrict__ bin,
                            const float* __restrict__ Wout, const float* __restrict__ bout,
                            float* __restrict__ qenc) {
    __shared__ float x[QLEN][EMBED];
    __shared__ float qkv[QLEN][3*EMBED];
    __shared__ float ctx[QLEN][EMBED];
    __shared__ float mctx[EMBED];
    int b = blockIdx.x;
    int t = threadIdx.x;   // 0..127

    for (int j = t; j < QLEN*EMBED; j += 128) {
        int q = j >> 6, d = j & 63;
        int w = qwords[b*QLEN + q];
        x[q][d] = word_w[(size_t)w * EMBED + d];
    }
    __syncthreads();

    for (int j = t; j < QLEN*192; j += 128) {
        int q = j / 192, o = j % 192;
        float acc = bin[o];
        const float* wrow = &Win[o*EMBED];
        #pragma unroll
        for (int d = 0; d < EMBED; ++d) acc += x[q][d] * wrow[d];
        qkv[q][o] = acc;
    }
    __syncthreads();

    if (t < 4*QLEN) {
        int h = t / QLEN, i = t % QLEN;
        float sc[QLEN];
        float mx = -1e30f;
        #pragma unroll
        for (int k = 0; k < QLEN; ++k) {
            float s = 0.f;
            #pragma unroll
            for (int d = 0; d < 16; ++d)
                s += qkv[i][h*16 + d] * qkv[k][EMBED + h*16 + d];
            s *= 0.25f;
            sc[k] = s;
            mx = fmaxf(mx, s);
        }
        float denom = 0.f;
        #pragma unroll
        for (int k = 0; k < QLEN; ++k) { sc[k] = expf(sc[k] - mx); denom += sc[k]; }
        float inv = 1.0f / denom;
        #pragma unroll
        for (int d = 0; d < 16; ++d) {
            float acc = 0.f;
            #pragma unroll
            for (int k = 0; k < QLEN; ++k)
                acc += sc[k] * qkv[k][2*EMBED + h*16 + d];
            ctx[i][h*16 + d] = acc * inv;
        }
    }
    __syncthreads();

    if (t < EMBED) {
        float acc = 0.f;
        #pragma unroll
        for (int q = 0; q < QLEN; ++q) acc += ctx[q][t];
        mctx[t] = acc * (1.0f/QLEN);
    }
    __syncthreads();

    if (t < EMBED) {
        float acc = bout[t];
        const float* wrow = &Wout[t*EMBED];
        #pragma unroll
        for (int d = 0; d < EMBED; ++d) acc += mctx[d] * wrow[d];
        qenc[b*EMBED + t] = acc;
    }
}

// ----------------------------------------------------------------- losses --
__device__ __forceinline__ float log_sigmoid(float x) {
    float l = log1pf(expf(-fabsf(x)));
    return x >= 0.f ? -l : x - l;
}
__device__ __forceinline__ float wred(float v) {
    #pragma unroll
    for (int off = 32; off; off >>= 1) v += __shfl_xor(v, off);
    return v;
}

__global__ void loss_kernel(const float* __restrict__ sel,
                            const float* __restrict__ qenc,
                            float* __restrict__ out) {
    int b = blockIdx.x;
    int d = threadIdx.x;   // 0..63
    const float scale = 0.25f;
    float u   = sel[(size_t)b*EMBED + d] * scale;
    float pos = sel[(size_t)(BATCH + b)*EMBED + d] * scale;
    float p   = qenc[b*EMBED + d] + 0.1f * u;

    float s_up = wred(u * pos);
    float s_pp = wred(p * pos);
    float nu[NNEG], np_[NNEG];
    #pragma unroll
    for (int n = 0; n < NNEG; ++n) {
        float ng = sel[(size_t)(2*BATCH + b*NNEG + n)*EMBED + d] * scale;
        nu[n]  = wred(u * ng);
        np_[n] = wred(p * ng);
    }
    if (d == 0) {
        float cf = 0.f, srch_neg = 0.f;
        #pragma unroll
        for (int n = 0; n < NNEG; ++n) {
            cf       += -log_sigmoid(s_up - nu[n]);
            srch_neg += -log_sigmoid(-np_[n]);
        }
        float res = cf * (1.0f/(BATCH*NNEG))
                  + (-log_sigmoid(s_pp)) * (1.0f/BATCH)
                  + srch_neg * (1.0f/(BATCH*NNEG));
        atomicAdd(out, res);
    }
}

// ---------------------------------------------------------------- launch ---
extern "C" void kernel_launch(void* const* d_in, const int* in_sizes, int n_in,
                              void* d_out, int out_size, void* d_ws, size_t ws_size,
                              hipStream_t stream) {
    const float* entity_w   = (const float*)d_in[0];
    const float* word_w     = (const float*)d_in[1];
    const float* in_proj_w  = (const float*)d_in[2];
    const float* in_proj_b  = (const float*)d_in[3];
    const float* out_proj_w = (const float*)d_in[4];
    const float* out_proj_b = (const float*)d_in[5];
    const float* edge_val   = (const float*)d_in[6];
    const int*   users      = (const int*)d_in[7];
    const int*   items      = (const int*)d_in[8];
    const int*   qwords     = (const int*)d_in[9];
    const int*   neg_items  = (const int*)d_in[10];
    const int*   edge_row   = (const int*)d_in[11];
    const int*   edge_col   = (const int*)d_in[12];
    float* out = (float*)d_out;

    const size_t HN  = (size_t)N_ENTITY * EMBED;       // 12.8M elems
    const size_t HNB = HN * sizeof(ushort16);          // 25.6 MB (bf16 buffer)

    // Region A (51.2MB): [ebuf_cr 25.6 | ebuf_v 12.8] -> later [e16 25.6 | h1 25.6]
    size_t need = HNB * 2                              // region A
                + sizeof(int) * (size_t)N_EDGES        // cols2
                + sizeof(ushort16) * (size_t)N_EDGES   // vals2
                + HNB                                  // h2 (bf16)
                + sizeof(float) * (size_t)NSEL * EMBED // sel
                + sizeof(float) * (size_t)BATCH * EMBED// qenc
                + sizeof(int) * (size_t)(N_ENTITY + 1) // rowptr
                + sizeof(unsigned int) * (size_t)BM_WORDS;

    hipMemsetAsync(out, 0, sizeof(float) * out_size, stream);

    if (ws_size >= need) {
        char* base = (char*)d_ws;
        int*       ebuf_cr = (int*)base;                       // 25.6 MB
        ushort16*  ebuf_v  = (ushort16*)(base + HNB);          // 12.8 MB
        ushort16*  e16     = (ushort16*)base;                  // alias (post-sort)
        ushort16*  h1      = (ushort16*)(base + HNB);          // alias (post-sort)
        char* p = base + 2 * HNB;
        int*       cols2   = (int*)p;        p += sizeof(int) * (size_t)N_EDGES;
        ushort16*  vals2   = (ushort16*)p;   p += sizeof(ushort16) * (size_t)N_EDGES;
        ushort16*  h2      = (ushort16*)p;   p += HNB;
        float*     sel     = (float*)p;      p += sizeof(float) * (size_t)NSEL * EMBED;
        float*     qenc    = (float*)p;      p += sizeof(float) * (size_t)BATCH * EMBED;
        int*       rowptr  = (int*)p;        p += sizeof(int) * (size_t)(N_ENTITY + 1);
        unsigned int* bmNeed = (unsigned int*)p;
        // build scratch overlaid on h2 (dead until spmm L2 writes needed rows)
        int* bucket_cnt = (int*)h2;
        int* bstart     = bucket_cnt + NBUCKET;
        int* blockBase  = bstart + NBUCKET + 1;   // 192*1563 ints ~1.2MB << 25.6MB

        hipMemsetAsync(bucket_cnt, 0, sizeof(int) * NBUCKET, stream);
        hipMemsetAsync(bmNeed, 0, sizeof(unsigned int) * BM_WORDS, stream);

        // --- atomic-free CSR build (bf16 vals) ---
        part_hist_kernel<<<NBLK_PART, 256, 0, stream>>>(edge_row, bucket_cnt, blockBase);
        bucket_scan_kernel<<<1, 256, 0, stream>>>(bucket_cnt, bstart);
        part_scatter_kernel<<<NBLK_PART, 256, 0, stream>>>(
            edge_row, edge_col, edge_val, bstart, blockBase, ebuf_cr, ebuf_v);
        bucket_sort_kernel<<<NBUCKET, 256, 0, stream>>>(
            ebuf_cr, ebuf_v, bstart, cols2, vals2, rowptr);

        need_build_kernel<<<(NSEL + 3) / 4, 256, 0, stream>>>(
            users, items, neg_items, rowptr, cols2, bmNeed);

        // entity -> bf16 (overwrites dead ebuf_cr region)
        conv_bf16_kernel<<<(N_ENTITY * EMBED / 4 + 255) / 256, 256, 0, stream>>>(
            entity_w, e16);

        // --- layer 0 (f32 precision) ---
        sel_init_kernel<<<(NSEL * EMBED) / 256, 256, 0, stream>>>(
            entity_w, users, items, neg_items, sel);

        // --- layer 1: full ---
        spmm_bf16_kernel<0><<<2048, 256, 0, stream>>>(e16, h1, rowptr, cols2, vals2, nullptr);
        sel_add_bf16_kernel<<<(NSEL * EMBED) / 256, 256, 0, stream>>>(
            h1, users, items, neg_items, sel);

        // --- layer 2: only rows needed downstream ---
        spmm_bf16_kernel<1><<<2048, 256, 0, stream>>>(h1, h2, rowptr, cols2, vals2, bmNeed);
        sel_add_bf16_kernel<<<(NSEL * EMBED) / 256, 256, 0, stream>>>(
            h2, users, items, neg_items, sel);

        // --- layer 3: direct pull into sel ---
        sel_pull_kernel<<<(NSEL + 3) / 4, 256, 0, stream>>>(
            h2, users, items, neg_items, rowptr, cols2, vals2, sel);

        sent_kernel<<<BATCH, 128, 0, stream>>>(qwords, word_w, in_proj_w, in_proj_b,
                                               out_proj_w, out_proj_b, qenc);
        loss_kernel<<<BATCH, 64, 0, stream>>>(sel, qenc, out);
    } else {
        // -------- fallback: atomic path (~105 MB ws) --------
        float* hA   = (float*)d_ws;
        float* hB   = hA + HN;
        float* sel  = hB + HN;
        float* qenc = sel + (size_t)NSEL * EMBED;
        unsigned int* bm = (unsigned int*)(qenc + (size_t)BATCH * EMBED);

        hipMemsetAsync(bm, 0, sizeof(unsigned int) * BM_WORDS, stream);
        bitmap_build_kernel<<<(NSEL + 255) / 256, 256, 0, stream>>>(users, items, neg_items, bm);
        sel_accum_kernel<<<(NSEL * EMBED) / 256, 256, 0, stream>>>(
            entity_w, users, items, neg_items, sel, 1);
        hipMemsetAsync(hA, 0, HN * sizeof(float), stream);
        spmm_kernel<<<2048, 256, 0, stream>>>(entity_w, hA, edge_row, edge_col, edge_val, N_EDGES);
        sel_accum_kernel<<<(NSEL * EMBED) / 256, 256, 0, stream>>>(
            hA, users, items, neg_items, sel, 0);
        hipMemsetAsync(hB, 0, HN * sizeof(float), stream);
        spmm_kernel<<<2048, 256, 0, stream>>>(hA, hB, edge_row, edge_col, edge_val, N_EDGES);
        sel_accum_kernel<<<(NSEL * EMBED) / 256, 256, 0, stream>>>(
            hB, users, items, neg_items, sel, 0);
        hipMemsetAsync(hA, 0, HN * sizeof(float), stream);
        spmm_filtered_kernel<<<2048, 256, 0, stream>>>(hB, hA, edge_row, edge_col, edge_val, bm, N_EDGES);
        sel_accum_kernel<<<(NSEL * EMBED) / 256, 256, 0, stream>>>(
            hA, users, items, neg_items, sel, 0);
        sent_kernel<<<BATCH, 128, 0, stream>>>(qwords, word_w, in_proj_w, in_proj_b,
                                               out_proj_w, out_proj_b, qenc);
        loss_kernel<<<BATCH, 64, 0, stream>>>(sel, qenc, out);
    }
}

// Round 6
// 708.340 us; speedup vs baseline: 6.5622x; 1.2036x over previous
//
#include <hip/hip_runtime.h>
#include <math.h>

#define N_ENTITY 200000
#define EMBED    64
#define N_EDGES  6400000
#define BATCH    1024
#define QLEN     20
#define NNEG     5
#define NSEL     (BATCH + BATCH + BATCH*NNEG)   // 7168 gathered rows
#define BM_WORDS ((N_ENTITY + 31) / 32)
#define COLMASK  0x3FFFF

#define BROWS     512                                // rows per bucket
#define ROWSH     9
#define NBUCKET   ((N_ENTITY + BROWS - 1) / BROWS)   // 391
#define NBLK_PART 512

typedef unsigned int   uint32;
typedef unsigned short ushort16;

__device__ __forceinline__ ushort16 f2bf(float f) {
    uint32 b = __float_as_uint(f);
    uint32 r = (b + 0x7FFFu + ((b >> 16) & 1u)) >> 16;   // RNE
    return (ushort16)r;
}
__device__ __forceinline__ float bf2f(ushort16 h) {
    return __uint_as_float(((uint32)h) << 16);
}

// ---------------------------------------------- sel helpers ---------------
__device__ __forceinline__ int sel_row(int i, const int* users, const int* items,
                                       const int* negs) {
    if (i < BATCH)        return users[i];
    if (i < 2 * BATCH)    return items[i - BATCH];
    return negs[i - 2 * BATCH];
}

// ------------------------------------------------------ edge partition ----
__global__ void part_hist_kernel(const int* __restrict__ erow,
                                 int* __restrict__ bucket_cnt,
                                 int* __restrict__ blockBase) {
    __shared__ int h[NBUCKET];
    int blk = blockIdx.x, t = threadIdx.x;
    for (int i = t; i < NBUCKET; i += 256) h[i] = 0;
    __syncthreads();
    int per = (N_EDGES + NBLK_PART - 1) / NBLK_PART;
    int s = blk * per, e = min(s + per, N_EDGES);
    for (int j = s + t; j < e; j += 256)
        atomicAdd(&h[erow[j] >> ROWSH], 1);
    __syncthreads();
    for (int i = t; i < NBUCKET; i += 256)
        blockBase[blk * NBUCKET + i] = atomicAdd(&bucket_cnt[i], h[i]);
}

__global__ void bucket_scan_kernel(const int* __restrict__ cnt,
                                   int* __restrict__ bstart) {
    __shared__ int s[256];
    int t = threadIdx.x;
    int i0 = t * 2, i1 = t * 2 + 1;
    int c0 = (i0 < NBUCKET) ? cnt[i0] : 0;
    int c1 = (i1 < NBUCKET) ? cnt[i1] : 0;
    s[t] = c0 + c1; __syncthreads();
    for (int off = 1; off < 256; off <<= 1) {
        int x = (t >= off) ? s[t - off] : 0;
        __syncthreads();
        s[t] += x;
        __syncthreads();
    }
    int excl = t ? s[t - 1] : 0;
    if (i0 <= NBUCKET) { if (i0 < NBUCKET) bstart[i0] = excl; else bstart[NBUCKET] = excl; }
    excl += c0;
    if (i1 <= NBUCKET) { if (i1 < NBUCKET) bstart[i1] = excl; else bstart[NBUCKET] = excl; }
    if (t == 255) bstart[NBUCKET] = s[255];   // = N_EDGES
}

// scatter into bucket-grouped combined int2 stream
__global__ void part_scatter_kernel(const int* __restrict__ erow,
                                    const int* __restrict__ ecol,
                                    const float* __restrict__ evalv,
                                    const int* __restrict__ bstart,
                                    const int* __restrict__ blockBase,
                                    int2* __restrict__ ebuf) {
    __shared__ int cur[NBUCKET];
    int blk = blockIdx.x, t = threadIdx.x;
    for (int i = t; i < NBUCKET; i += 256)
        cur[i] = bstart[i] + blockBase[blk * NBUCKET + i];
    __syncthreads();
    int per = (N_EDGES + NBLK_PART - 1) / NBLK_PART;
    int s = blk * per, e = min(s + per, N_EDGES);
    int j = s + t;
    for (; j + 256 < e; j += 512) {
        int   r0 = erow[j],       r1 = erow[j + 256];
        int   c0 = ecol[j],       c1 = ecol[j + 256];
        float v0 = evalv[j],      v1 = evalv[j + 256];
        int p0 = atomicAdd(&cur[r0 >> ROWSH], 1);
        int p1 = atomicAdd(&cur[r1 >> ROWSH], 1);
        ebuf[p0] = make_int2(c0 | ((r0 & (BROWS-1)) << 18), (int)f2bf(v0));
        ebuf[p1] = make_int2(c1 | ((r1 & (BROWS-1)) << 18), (int)f2bf(v1));
    }
    for (; j < e; j += 256) {
        int   r = erow[j];
        int   c = ecol[j];
        float v = evalv[j];
        int pos = atomicAdd(&cur[r >> ROWSH], 1);
        ebuf[pos] = make_int2(c | ((r & (BROWS-1)) << 18), (int)f2bf(v));
    }
}

// --------------------------- bucket-local counting sort -> exact CSR ------
// 512 threads/block; hist/scan map 1:1 to the 512 rows of the bucket.
__global__ void bucket_sort_kernel(const int2* __restrict__ ebuf,
                                   const int* __restrict__ bstart,
                                   int2* __restrict__ ebuf2,
                                   int* __restrict__ rowptr) {
    __shared__ int cur[BROWS];
    int b = blockIdx.x, t = threadIdx.x;   // t in [0,512)
    int beg = bstart[b], end = bstart[b + 1];
    cur[t] = 0;
    __syncthreads();
    for (int j = beg + t; j < end; j += BROWS)
        atomicAdd(&cur[((unsigned)ebuf[j].x) >> 18], 1);
    __syncthreads();
    int own = cur[t];
    __syncthreads();
    // Hillis-Steele inclusive scan over 512 entries
    cur[t] = own;
    __syncthreads();
    for (int off = 1; off < BROWS; off <<= 1) {
        int x = (t >= off) ? cur[t - off] : 0;
        __syncthreads();
        cur[t] += x;
        __syncthreads();
    }
    int excl = cur[t] - own;
    __syncthreads();
    int r = (b << ROWSH) + t;
    if (r <= N_ENTITY) rowptr[r] = beg + excl;
    cur[t] = beg + excl;
    __syncthreads();
    for (int j = beg + t; j < end; j += BROWS) {
        int2 e = ebuf[j];
        int pos = atomicAdd(&cur[((unsigned)e.x) >> 18], 1);   // LDS atomic
        ebuf2[pos] = e;
    }
}

// ---------------------- needed-rows bitmap (sel rows + their neighbors) ---
__global__ void need_build_kernel(const int* __restrict__ users,
                                  const int* __restrict__ items,
                                  const int* __restrict__ negs,
                                  const int* __restrict__ rowptr,
                                  const int2* __restrict__ edges,
                                  unsigned int* __restrict__ bm) {
    int lane = threadIdx.x & 63;
    int wave = blockIdx.x * (blockDim.x >> 6) + (threadIdx.x >> 6);
    if (wave >= NSEL) return;
    int idx = sel_row(wave, users, items, negs);
    if (lane == 0) atomicOr(&bm[idx >> 5], 1u << (idx & 31));
    int beg = rowptr[idx], end = rowptr[idx + 1];
    for (int j = beg + lane; j < end; j += 64) {
        int c = edges[j].x & COLMASK;
        atomicOr(&bm[c >> 5], 1u << (c & 31));
    }
}

// ----------------------------------------------- entity -> bf16 convert ---
__global__ void conv_bf16_kernel(const float* __restrict__ src,
                                 ushort16* __restrict__ dst) {
    int i = (blockIdx.x * blockDim.x + threadIdx.x) * 4;
    if (i >= N_ENTITY * EMBED) return;
    float4 v = *(const float4*)&src[i];
    uint32 p0 = (uint32)f2bf(v.x) | ((uint32)f2bf(v.y) << 16);
    uint32 p1 = (uint32)f2bf(v.z) | ((uint32)f2bf(v.w) << 16);
    *(uint2*)&dst[i] = make_uint2(p0, p1);
}

// --------------------------------------------------- bf16 CSR SpMM --------
// 2 edges per wave: half = lane>>5 picks edge parity, lane&31 = dim-pair.
template<int FILTER>
__global__ void spmm_bf16_kernel(const ushort16* __restrict__ src,
                                 ushort16* __restrict__ dst,
                                 const int* __restrict__ rowptr,
                                 const int2* __restrict__ edges,
                                 const unsigned int* __restrict__ bm) {
    int lane = threadIdx.x & 63;
    int half = lane >> 5;
    int l2   = lane & 31;
    int wave  = blockIdx.x * (blockDim.x >> 6) + (threadIdx.x >> 6);
    int nwave = gridDim.x * (blockDim.x >> 6);
    for (int row = wave; row < N_ENTITY; row += nwave) {
        if (FILTER && !((bm[row >> 5] >> (row & 31)) & 1u)) continue;
        int beg = rowptr[row], end = rowptr[row + 1];
        float ax = 0.f, ay = 0.f;
        int j = beg + half;
        for (; j + 2 < end; j += 4) {            // 2 edges per half per iter
            int2 e0 = edges[j], e1 = edges[j + 2];
            float v0 = bf2f((ushort16)(e0.y & 0xFFFF));
            float v1 = bf2f((ushort16)(e1.y & 0xFFFF));
            uint32 p0 = *(const uint32*)&src[(size_t)(e0.x & COLMASK) * EMBED + l2 * 2];
            uint32 p1 = *(const uint32*)&src[(size_t)(e1.x & COLMASK) * EMBED + l2 * 2];
            ax += v0 * __uint_as_float(p0 << 16);
            ay += v0 * __uint_as_float(p0 & 0xFFFF0000u);
            ax += v1 * __uint_as_float(p1 << 16);
            ay += v1 * __uint_as_float(p1 & 0xFFFF0000u);
        }
        for (; j < end; j += 2) {
            int2 e = edges[j];
            float v = bf2f((ushort16)(e.y & 0xFFFF));
            uint32 p = *(const uint32*)&src[(size_t)(e.x & COLMASK) * EMBED + l2 * 2];
            ax += v * __uint_as_float(p << 16);
            ay += v * __uint_as_float(p & 0xFFFF0000u);
        }
        ax += __shfl_xor(ax, 32);
        ay += __shfl_xor(ay, 32);
        if (half == 0) {
            uint32 packed = (uint32)f2bf(ax) | ((uint32)f2bf(ay) << 16);
            *(uint32*)&dst[(size_t)row * EMBED + l2 * 2] = packed;
        }
    }
}

// layer-3 direct pull: sel[i] += sum_j val * h2[col]   (h2 bf16)
__global__ void sel_pull_kernel(const ushort16* __restrict__ h,
                                const int* __restrict__ users,
                                const int* __restrict__ items,
                                const int* __restrict__ negs,
                                const int* __restrict__ rowptr,
                                const int2* __restrict__ edges,
                                float* __restrict__ sel) {
    int lane = threadIdx.x & 63;
    int wave = blockIdx.x * (blockDim.x >> 6) + (threadIdx.x >> 6);
    if (wave >= NSEL) return;
    int idx = sel_row(wave, users, items, negs);
    int beg = rowptr[idx], end = rowptr[idx + 1];
    float acc = 0.f;
    int j = beg;
    for (; j + 2 <= end; j += 2) {
        int2 e0 = edges[j], e1 = edges[j + 1];
        float v0 = bf2f((ushort16)(e0.y & 0xFFFF));
        float v1 = bf2f((ushort16)(e1.y & 0xFFFF));
        acc += v0 * bf2f(h[(size_t)(e0.x & COLMASK) * EMBED + lane]);
        acc += v1 * bf2f(h[(size_t)(e1.x & COLMASK) * EMBED + lane]);
    }
    for (; j < end; ++j) {
        int2 e = edges[j];
        acc += bf2f((ushort16)(e.y & 0xFFFF)) * bf2f(h[(size_t)(e.x & COLMASK) * EMBED + lane]);
    }
    sel[(size_t)wave * EMBED + lane] += acc;
}

// ------------------------------------------------- sel accumulate ---------
__global__ void sel_init_kernel(const float* __restrict__ h,
                                const int* __restrict__ users,
                                const int* __restrict__ items,
                                const int* __restrict__ negs,
                                float* __restrict__ sel) {
    int tid = blockIdx.x * blockDim.x + threadIdx.x;
    if (tid >= NSEL * EMBED) return;
    int i = tid >> 6, d = tid & 63;
    int idx = sel_row(i, users, items, negs);
    sel[tid] = h[(size_t)idx * EMBED + d];
}

__global__ void sel_add_bf16_kernel(const ushort16* __restrict__ h,
                                    const int* __restrict__ users,
                                    const int* __restrict__ items,
                                    const int* __restrict__ negs,
                                    float* __restrict__ sel) {
    int tid = blockIdx.x * blockDim.x + threadIdx.x;
    if (tid >= NSEL * EMBED) return;
    int i = tid >> 6, d = tid & 63;
    int idx = sel_row(i, users, items, negs);
    sel[tid] += bf2f(h[(size_t)idx * EMBED + d]);
}

// --------------------------------------- fallback (atomic) path -----------
__global__ void spmm_kernel(const float* __restrict__ src, float* __restrict__ dst,
                            const int* __restrict__ erow, const int* __restrict__ ecol,
                            const float* __restrict__ evalv, int n_edges) {
    int lane  = threadIdx.x & 63;
    int wave  = blockIdx.x * (blockDim.x >> 6) + (threadIdx.x >> 6);
    int nwave = gridDim.x * (blockDim.x >> 6);
    for (int e = wave; e < n_edges; e += nwave) {
        int   r = erow[e];
        int   c = ecol[e];
        float v = evalv[e];
        float x = src[(size_t)c * EMBED + lane];
        atomicAdd(&dst[(size_t)r * EMBED + lane], v * x);
    }
}

__global__ void spmm_filtered_kernel(const float* __restrict__ src, float* __restrict__ dst,
                                     const int* __restrict__ erow, const int* __restrict__ ecol,
                                     const float* __restrict__ evalv,
                                     const unsigned int* __restrict__ bm, int n_edges) {
    int lane  = threadIdx.x & 63;
    int wave  = blockIdx.x * (blockDim.x >> 6) + (threadIdx.x >> 6);
    int nwave = gridDim.x * (blockDim.x >> 6);
    for (int e = wave; e < n_edges; e += nwave) {
        int r = erow[e];
        if (!((bm[r >> 5] >> (r & 31)) & 1u)) continue;
        int   c = ecol[e];
        float v = evalv[e];
        float x = src[(size_t)c * EMBED + lane];
        atomicAdd(&dst[(size_t)r * EMBED + lane], v * x);
    }
}

__global__ void bitmap_build_kernel(const int* __restrict__ users,
                                    const int* __restrict__ items,
                                    const int* __restrict__ negs,
                                    unsigned int* __restrict__ bm) {
    int i = blockIdx.x * blockDim.x + threadIdx.x;
    if (i >= NSEL) return;
    int idx = sel_row(i, users, items, negs);
    atomicOr(&bm[idx >> 5], 1u << (idx & 31));
}

__global__ void sel_accum_kernel(const float* __restrict__ h,
                                 const int* __restrict__ users,
                                 const int* __restrict__ items,
                                 const int* __restrict__ negs,
                                 float* __restrict__ sel, int init) {
    int tid = blockIdx.x * blockDim.x + threadIdx.x;
    if (tid >= NSEL * EMBED) return;
    int i = tid >> 6, d = tid & 63;
    int idx = sel_row(i, users, items, negs);
    float v = h[(size_t)idx * EMBED + d];
    if (init) sel[tid] = v;
    else      sel[tid] += v;
}

// -------------------------------------------------------- sentence encode --
__global__ void sent_kernel(const int* __restrict__ qwords,
                            const float* __restrict__ word_w,
                            const float* __restrict__ Win,  const float* __restrict__ bin,
                            const float* __restrict__ Wout, const float* __restrict__ bout,
                            float* __restrict__ qenc) {
    __shared__ float x[QLEN][EMBED];
    __shared__ float qkv[QLEN][3*EMBED];
    __shared__ float ctx[QLEN][EMBED];
    __shared__ float mctx[EMBED];
    int b = blockIdx.x;
    int t = threadIdx.x;   // 0..127

    for (int j = t; j < QLEN*EMBED; j += 128) {
        int q = j >> 6, d = j & 63;
        int w = qwords[b*QLEN + q];
        x[q][d] = word_w[(size_t)w * EMBED + d];
    }
    __syncthreads();

    for (int j = t; j < QLEN*192; j += 128) {
        int q = j / 192, o = j % 192;
        float acc = bin[o];
        const float* wrow = &Win[o*EMBED];
        #pragma unroll
        for (int d = 0; d < EMBED; ++d) acc += x[q][d] * wrow[d];
        qkv[q][o] = acc;
    }
    __syncthreads();

    if (t < 4*QLEN) {
        int h = t / QLEN, i = t % QLEN;
        float sc[QLEN];
        float mx = -1e30f;
        #pragma unroll
        for (int k = 0; k < QLEN; ++k) {
            float s = 0.f;
            #pragma unroll
            for (int d = 0; d < 16; ++d)
                s += qkv[i][h*16 + d] * qkv[k][EMBED + h*16 + d];
            s *= 0.25f;
            sc[k] = s;
            mx = fmaxf(mx, s);
        }
        float denom = 0.f;
        #pragma unroll
        for (int k = 0; k < QLEN; ++k) { sc[k] = expf(sc[k] - mx); denom += sc[k]; }
        float inv = 1.0f / denom;
        #pragma unroll
        for (int d = 0; d < 16; ++d) {
            float acc = 0.f;
            #pragma unroll
            for (int k = 0; k < QLEN; ++k)
                acc += sc[k] * qkv[k][2*EMBED + h*16 + d];
            ctx[i][h*16 + d] = acc * inv;
        }
    }
    __syncthreads();

    if (t < EMBED) {
        float acc = 0.f;
        #pragma unroll
        for (int q = 0; q < QLEN; ++q) acc += ctx[q][t];
        mctx[t] = acc * (1.0f/QLEN);
    }
    __syncthreads();

    if (t < EMBED) {
        float acc = bout[t];
        const float* wrow = &Wout[t*EMBED];
        #pragma unroll
        for (int d = 0; d < EMBED; ++d) acc += mctx[d] * wrow[d];
        qenc[b*EMBED + t] = acc;
    }
}

// ----------------------------------------------------------------- losses --
__device__ __forceinline__ float log_sigmoid(float x) {
    float l = log1pf(expf(-fabsf(x)));
    return x >= 0.f ? -l : x - l;
}
__device__ __forceinline__ float wred(float v) {
    #pragma unroll
    for (int off = 32; off; off >>= 1) v += __shfl_xor(v, off);
    return v;
}

__global__ void loss_kernel(const float* __restrict__ sel,
                            const float* __restrict__ qenc,
                            float* __restrict__ out) {
    int b = blockIdx.x;
    int d = threadIdx.x;   // 0..63
    const float scale = 0.25f;
    float u   = sel[(size_t)b*EMBED + d] * scale;
    float pos = sel[(size_t)(BATCH + b)*EMBED + d] * scale;
    float p   = qenc[b*EMBED + d] + 0.1f * u;

    float s_up = wred(u * pos);
    float s_pp = wred(p * pos);
    float nu[NNEG], np_[NNEG];
    #pragma unroll
    for (int n = 0; n < NNEG; ++n) {
        float ng = sel[(size_t)(2*BATCH + b*NNEG + n)*EMBED + d] * scale;
        nu[n]  = wred(u * ng);
        np_[n] = wred(p * ng);
    }
    if (d == 0) {
        float cf = 0.f, srch_neg = 0.f;
        #pragma unroll
        for (int n = 0; n < NNEG; ++n) {
            cf       += -log_sigmoid(s_up - nu[n]);
            srch_neg += -log_sigmoid(-np_[n]);
        }
        float res = cf * (1.0f/(BATCH*NNEG))
                  + (-log_sigmoid(s_pp)) * (1.0f/BATCH)
                  + srch_neg * (1.0f/(BATCH*NNEG));
        atomicAdd(out, res);
    }
}

// ---------------------------------------------------------------- launch ---
extern "C" void kernel_launch(void* const* d_in, const int* in_sizes, int n_in,
                              void* d_out, int out_size, void* d_ws, size_t ws_size,
                              hipStream_t stream) {
    const float* entity_w   = (const float*)d_in[0];
    const float* word_w     = (const float*)d_in[1];
    const float* in_proj_w  = (const float*)d_in[2];
    const float* in_proj_b  = (const float*)d_in[3];
    const float* out_proj_w = (const float*)d_in[4];
    const float* out_proj_b = (const float*)d_in[5];
    const float* edge_val   = (const float*)d_in[6];
    const int*   users      = (const int*)d_in[7];
    const int*   items      = (const int*)d_in[8];
    const int*   qwords     = (const int*)d_in[9];
    const int*   neg_items  = (const int*)d_in[10];
    const int*   edge_row   = (const int*)d_in[11];
    const int*   edge_col   = (const int*)d_in[12];
    float* out = (float*)d_out;

    const size_t HN  = (size_t)N_ENTITY * EMBED;       // 12.8M elems
    const size_t HNB = HN * sizeof(ushort16);          // 25.6 MB (bf16 buffer)
    const size_t EB  = sizeof(int2) * (size_t)N_EDGES; // 51.2 MB

    // Layout: ebuf2 | regionA(ebuf -> e16+h1) | h2 | sel | qenc | rowptr | bm
    size_t need = EB                                   // ebuf2
                + EB                                   // region A
                + HNB                                  // h2
                + sizeof(float) * (size_t)NSEL * EMBED // sel
                + sizeof(float) * (size_t)BATCH * EMBED// qenc
                + sizeof(int) * (size_t)(N_ENTITY + 1) // rowptr
                + sizeof(unsigned int) * (size_t)BM_WORDS;

    hipMemsetAsync(out, 0, sizeof(float) * out_size, stream);

    if (ws_size >= need) {
        char* base = (char*)d_ws;
        int2*      ebuf2 = (int2*)base;
        int2*      ebuf  = (int2*)(base + EB);                 // region A
        ushort16*  e16   = (ushort16*)(base + EB);             // alias post-sort
        ushort16*  h1    = (ushort16*)(base + EB + HNB);       // alias post-sort
        char* p = base + 2 * EB;
        ushort16*  h2    = (ushort16*)p;     p += HNB;
        float*     sel   = (float*)p;        p += sizeof(float) * (size_t)NSEL * EMBED;
        float*     qenc  = (float*)p;        p += sizeof(float) * (size_t)BATCH * EMBED;
        int*       rowptr = (int*)p;         p += sizeof(int) * (size_t)(N_ENTITY + 1);
        unsigned int* bmNeed = (unsigned int*)p;
        // build scratch overlaid on h2 (dead until spmm L2 writes needed rows)
        int* bucket_cnt = (int*)h2;
        int* bstart     = bucket_cnt + NBUCKET;
        int* blockBase  = bstart + NBUCKET + 1;   // 512*391 ints ~0.8MB << 25.6MB

        hipMemsetAsync(bucket_cnt, 0, sizeof(int) * NBUCKET, stream);
        hipMemsetAsync(bmNeed, 0, sizeof(unsigned int) * BM_WORDS, stream);

        // --- atomic-free CSR build (combined int2 stream) ---
        part_hist_kernel<<<NBLK_PART, 256, 0, stream>>>(edge_row, bucket_cnt, blockBase);
        bucket_scan_kernel<<<1, 256, 0, stream>>>(bucket_cnt, bstart);
        part_scatter_kernel<<<NBLK_PART, 256, 0, stream>>>(
            edge_row, edge_col, edge_val, bstart, blockBase, ebuf);
        bucket_sort_kernel<<<NBUCKET, BROWS, 0, stream>>>(ebuf, bstart, ebuf2, rowptr);

        need_build_kernel<<<(NSEL + 3) / 4, 256, 0, stream>>>(
            users, items, neg_items, rowptr, ebuf2, bmNeed);

        // entity -> bf16 (overwrites dead ebuf region)
        conv_bf16_kernel<<<(N_ENTITY * EMBED / 4 + 255) / 256, 256, 0, stream>>>(
            entity_w, e16);

        // --- layer 0 (f32 precision) ---
        sel_init_kernel<<<(NSEL * EMBED) / 256, 256, 0, stream>>>(
            entity_w, users, items, neg_items, sel);

        // --- layer 1: full ---
        spmm_bf16_kernel<0><<<2048, 256, 0, stream>>>(e16, h1, rowptr, ebuf2, nullptr);
        sel_add_bf16_kernel<<<(NSEL * EMBED) / 256, 256, 0, stream>>>(
            h1, users, items, neg_items, sel);

        // --- layer 2: only rows needed downstream ---
        spmm_bf16_kernel<1><<<2048, 256, 0, stream>>>(h1, h2, rowptr, ebuf2, bmNeed);
        sel_add_bf16_kernel<<<(NSEL * EMBED) / 256, 256, 0, stream>>>(
            h2, users, items, neg_items, sel);

        // --- layer 3: direct pull into sel ---
        sel_pull_kernel<<<(NSEL + 3) / 4, 256, 0, stream>>>(
            h2, users, items, neg_items, rowptr, ebuf2, sel);

        sent_kernel<<<BATCH, 128, 0, stream>>>(qwords, word_w, in_proj_w, in_proj_b,
                                               out_proj_w, out_proj_b, qenc);
        loss_kernel<<<BATCH, 64, 0, stream>>>(sel, qenc, out);
    } else {
        // -------- fallback: atomic path (~105 MB ws) --------
        float* hA   = (float*)d_ws;
        float* hB   = hA + HN;
        float* sel  = hB + HN;
        float* qenc = sel + (size_t)NSEL * EMBED;
        unsigned int* bm = (unsigned int*)(qenc + (size_t)BATCH * EMBED);

        hipMemsetAsync(bm, 0, sizeof(unsigned int) * BM_WORDS, stream);
        bitmap_build_kernel<<<(NSEL + 255) / 256, 256, 0, stream>>>(users, items, neg_items, bm);
        sel_accum_kernel<<<(NSEL * EMBED) / 256, 256, 0, stream>>>(
            entity_w, users, items, neg_items, sel, 1);
        hipMemsetAsync(hA, 0, HN * sizeof(float), stream);
        spmm_kernel<<<2048, 256, 0, stream>>>(entity_w, hA, edge_row, edge_col, edge_val, N_EDGES);
        sel_accum_kernel<<<(NSEL * EMBED) / 256, 256, 0, stream>>>(
            hA, users, items, neg_items, sel, 0);
        hipMemsetAsync(hB, 0, HN * sizeof(float), stream);
        spmm_kernel<<<2048, 256, 0, stream>>>(hA, hB, edge_row, edge_col, edge_val, N_EDGES);
        sel_accum_kernel<<<(NSEL * EMBED) / 256, 256, 0, stream>>>(
            hB, users, items, neg_items, sel, 0);
        hipMemsetAsync(hA, 0, HN * sizeof(float), stream);
        spmm_filtered_kernel<<<2048, 256, 0, stream>>>(hB, hA, edge_row, edge_col, edge_val, bm, N_EDGES);
        sel_accum_kernel<<<(NSEL * EMBED) / 256, 256, 0, stream>>>(
            hA, users, items, neg_items, sel, 0);
        sent_kernel<<<BATCH, 128, 0, stream>>>(qwords, word_w, in_proj_w, in_proj_b,
                                               out_proj_w, out_proj_b, qenc);
        loss_kernel<<<BATCH, 64, 0, stream>>>(sel, qenc, out);
    }
}

// Round 7
// 628.062 us; speedup vs baseline: 7.4010x; 1.1278x over previous
//
#include <hip/hip_runtime.h>
#include <math.h>

#define N_ENTITY 200000
#define EMBED    64
#define N_EDGES  6400000
#define BATCH    1024
#define QLEN     20
#define NNEG     5
#define NSEL     (BATCH + BATCH + BATCH*NNEG)   // 7168 gathered rows
#define BM_WORDS ((N_ENTITY + 31) / 32)
#define COLMASK  0x3FFFF

#define BROWS     512                                // rows per bucket
#define ROWSH     9
#define NBUCKET   ((N_ENTITY + BROWS - 1) / BROWS)   // 391
#define NBLK_PART 512

typedef unsigned int   uint32;
typedef unsigned short ushort16;

__device__ __forceinline__ ushort16 f2bf(float f) {
    uint32 b = __float_as_uint(f);
    uint32 r = (b + 0x7FFFu + ((b >> 16) & 1u)) >> 16;   // RNE
    return (ushort16)r;
}
__device__ __forceinline__ float bf2f(ushort16 h) {
    return __uint_as_float(((uint32)h) << 16);
}
__device__ __forceinline__ float bflo(uint32 p) { return __uint_as_float(p << 16); }
__device__ __forceinline__ float bfhi(uint32 p) { return __uint_as_float(p & 0xFFFF0000u); }

// ---------------------------------------------- sel helpers ---------------
__device__ __forceinline__ int sel_row(int i, const int* users, const int* items,
                                       const int* negs) {
    if (i < BATCH)        return users[i];
    if (i < 2 * BATCH)    return items[i - BATCH];
    return negs[i - 2 * BATCH];
}

// ------------------------------------------------------ edge partition ----
__global__ void part_hist_kernel(const int* __restrict__ erow,
                                 int* __restrict__ bucket_cnt,
                                 int* __restrict__ blockBase) {
    __shared__ int h[NBUCKET];
    int blk = blockIdx.x, t = threadIdx.x;
    for (int i = t; i < NBUCKET; i += 256) h[i] = 0;
    __syncthreads();
    int per = (N_EDGES + NBLK_PART - 1) / NBLK_PART;
    int s = blk * per, e = min(s + per, N_EDGES);
    for (int j = s + t; j < e; j += 256)
        atomicAdd(&h[erow[j] >> ROWSH], 1);
    __syncthreads();
    for (int i = t; i < NBUCKET; i += 256)
        blockBase[blk * NBUCKET + i] = atomicAdd(&bucket_cnt[i], h[i]);
}

__global__ void bucket_scan_kernel(const int* __restrict__ cnt,
                                   int* __restrict__ bstart) {
    __shared__ int s[256];
    int t = threadIdx.x;
    int i0 = t * 2, i1 = t * 2 + 1;
    int c0 = (i0 < NBUCKET) ? cnt[i0] : 0;
    int c1 = (i1 < NBUCKET) ? cnt[i1] : 0;
    s[t] = c0 + c1; __syncthreads();
    for (int off = 1; off < 256; off <<= 1) {
        int x = (t >= off) ? s[t - off] : 0;
        __syncthreads();
        s[t] += x;
        __syncthreads();
    }
    int excl = t ? s[t - 1] : 0;
    if (i0 <= NBUCKET) { if (i0 < NBUCKET) bstart[i0] = excl; else bstart[NBUCKET] = excl; }
    excl += c0;
    if (i1 <= NBUCKET) { if (i1 < NBUCKET) bstart[i1] = excl; else bstart[NBUCKET] = excl; }
    if (t == 255) bstart[NBUCKET] = s[255];   // = N_EDGES
}

// scatter into bucket-grouped combined int2 stream
__global__ void part_scatter_kernel(const int* __restrict__ erow,
                                    const int* __restrict__ ecol,
                                    const float* __restrict__ evalv,
                                    const int* __restrict__ bstart,
                                    const int* __restrict__ blockBase,
                                    int2* __restrict__ ebuf) {
    __shared__ int cur[NBUCKET];
    int blk = blockIdx.x, t = threadIdx.x;
    for (int i = t; i < NBUCKET; i += 256)
        cur[i] = bstart[i] + blockBase[blk * NBUCKET + i];
    __syncthreads();
    int per = (N_EDGES + NBLK_PART - 1) / NBLK_PART;
    int s = blk * per, e = min(s + per, N_EDGES);
    int j = s + t;
    for (; j + 256 < e; j += 512) {
        int   r0 = erow[j],       r1 = erow[j + 256];
        int   c0 = ecol[j],       c1 = ecol[j + 256];
        float v0 = evalv[j],      v1 = evalv[j + 256];
        int p0 = atomicAdd(&cur[r0 >> ROWSH], 1);
        int p1 = atomicAdd(&cur[r1 >> ROWSH], 1);
        ebuf[p0] = make_int2(c0 | ((r0 & (BROWS-1)) << 18), (int)f2bf(v0));
        ebuf[p1] = make_int2(c1 | ((r1 & (BROWS-1)) << 18), (int)f2bf(v1));
    }
    for (; j < e; j += 256) {
        int   r = erow[j];
        int   c = ecol[j];
        float v = evalv[j];
        int pos = atomicAdd(&cur[r >> ROWSH], 1);
        ebuf[pos] = make_int2(c | ((r & (BROWS-1)) << 18), (int)f2bf(v));
    }
}

// --------------------------- bucket-local counting sort -> exact CSR ------
__global__ void bucket_sort_kernel(const int2* __restrict__ ebuf,
                                   const int* __restrict__ bstart,
                                   int2* __restrict__ ebuf2,
                                   int* __restrict__ rowptr) {
    __shared__ int cur[BROWS];
    int b = blockIdx.x, t = threadIdx.x;   // t in [0,512)
    int beg = bstart[b], end = bstart[b + 1];
    cur[t] = 0;
    __syncthreads();
    for (int j = beg + t; j < end; j += BROWS)
        atomicAdd(&cur[((unsigned)ebuf[j].x) >> 18], 1);
    __syncthreads();
    int own = cur[t];
    __syncthreads();
    cur[t] = own;
    __syncthreads();
    for (int off = 1; off < BROWS; off <<= 1) {
        int x = (t >= off) ? cur[t - off] : 0;
        __syncthreads();
        cur[t] += x;
        __syncthreads();
    }
    int excl = cur[t] - own;
    __syncthreads();
    int r = (b << ROWSH) + t;
    if (r <= N_ENTITY) rowptr[r] = beg + excl;
    cur[t] = beg + excl;
    __syncthreads();
    for (int j = beg + t; j < end; j += BROWS) {
        int2 e = ebuf[j];
        int pos = atomicAdd(&cur[((unsigned)e.x) >> 18], 1);   // LDS atomic
        ebuf2[pos] = e;
    }
}

// ---------------------- needed-rows bitmap (sel rows + their neighbors) ---
__global__ void need_build_kernel(const int* __restrict__ users,
                                  const int* __restrict__ items,
                                  const int* __restrict__ negs,
                                  const int* __restrict__ rowptr,
                                  const int2* __restrict__ edges,
                                  unsigned int* __restrict__ bm) {
    int lane = threadIdx.x & 63;
    int wave = blockIdx.x * (blockDim.x >> 6) + (threadIdx.x >> 6);
    if (wave >= NSEL) return;
    int idx = sel_row(wave, users, items, negs);
    if (lane == 0) atomicOr(&bm[idx >> 5], 1u << (idx & 31));
    int beg = rowptr[idx], end = rowptr[idx + 1];
    for (int j = beg + lane; j < end; j += 64) {
        int c = edges[j].x & COLMASK;
        atomicOr(&bm[c >> 5], 1u << (c & 31));
    }
}

// ----------------------------------------------- entity -> bf16 convert ---
__global__ void conv_bf16_kernel(const float* __restrict__ src,
                                 ushort16* __restrict__ dst) {
    int i = (blockIdx.x * blockDim.x + threadIdx.x) * 4;
    if (i >= N_ENTITY * EMBED) return;
    float4 v = *(const float4*)&src[i];
    uint32 p0 = (uint32)f2bf(v.x) | ((uint32)f2bf(v.y) << 16);
    uint32 p1 = (uint32)f2bf(v.z) | ((uint32)f2bf(v.w) << 16);
    *(uint2*)&dst[i] = make_uint2(p0, p1);
}

// --------------------------------------------------- bf16 CSR SpMM --------
// Each 32-lane half takes a CONTIGUOUS half of the row's edges (adjacent
// int2 loads merge into dwordx4) and runs a 4-deep gather unroll: 8 gathers
// in flight per wave to hide L2/L3 miss latency.
template<int FILTER>
__global__ void spmm_bf16_kernel(const ushort16* __restrict__ src,
                                 ushort16* __restrict__ dst,
                                 const int* __restrict__ rowptr,
                                 const int2* __restrict__ edges,
                                 const unsigned int* __restrict__ bm) {
    int lane = threadIdx.x & 63;
    int half = lane >> 5;
    int l2   = lane & 31;
    int wave  = blockIdx.x * (blockDim.x >> 6) + (threadIdx.x >> 6);
    int nwave = gridDim.x * (blockDim.x >> 6);
    for (int row = wave; row < N_ENTITY; row += nwave) {
        if (FILTER && !((bm[row >> 5] >> (row & 31)) & 1u)) continue;
        int beg = rowptr[row], end = rowptr[row + 1];
        int cnt = end - beg;
        int h0  = cnt - (cnt >> 1);               // ceil half for half 0
        int s   = beg + half * h0;
        int e   = half ? end : (beg + h0);
        float ax = 0.f, ay = 0.f;
        int j = s;
        for (; j + 3 < e; j += 4) {
            int2 e0 = edges[j], e1 = edges[j+1], e2 = edges[j+2], e3 = edges[j+3];
            uint32 p0 = *(const uint32*)&src[(size_t)(e0.x & COLMASK) * EMBED + l2 * 2];
            uint32 p1 = *(const uint32*)&src[(size_t)(e1.x & COLMASK) * EMBED + l2 * 2];
            uint32 p2 = *(const uint32*)&src[(size_t)(e2.x & COLMASK) * EMBED + l2 * 2];
            uint32 p3 = *(const uint32*)&src[(size_t)(e3.x & COLMASK) * EMBED + l2 * 2];
            float v0 = bf2f((ushort16)(e0.y & 0xFFFF));
            float v1 = bf2f((ushort16)(e1.y & 0xFFFF));
            float v2 = bf2f((ushort16)(e2.y & 0xFFFF));
            float v3 = bf2f((ushort16)(e3.y & 0xFFFF));
            ax += v0 * bflo(p0);  ay += v0 * bfhi(p0);
            ax += v1 * bflo(p1);  ay += v1 * bfhi(p1);
            ax += v2 * bflo(p2);  ay += v2 * bfhi(p2);
            ax += v3 * bflo(p3);  ay += v3 * bfhi(p3);
        }
        for (; j < e; ++j) {
            int2 ed = edges[j];
            float v = bf2f((ushort16)(ed.y & 0xFFFF));
            uint32 p = *(const uint32*)&src[(size_t)(ed.x & COLMASK) * EMBED + l2 * 2];
            ax += v * bflo(p);
            ay += v * bfhi(p);
        }
        ax += __shfl_xor(ax, 32);
        ay += __shfl_xor(ay, 32);
        if (half == 0) {
            uint32 packed = (uint32)f2bf(ax) | ((uint32)f2bf(ay) << 16);
            *(uint32*)&dst[(size_t)row * EMBED + l2 * 2] = packed;
        }
    }
}

// layer-3 direct pull: sel[i] += sum_j val * h2[col]   (h2 bf16)
__global__ void sel_pull_kernel(const ushort16* __restrict__ h,
                                const int* __restrict__ users,
                                const int* __restrict__ items,
                                const int* __restrict__ negs,
                                const int* __restrict__ rowptr,
                                const int2* __restrict__ edges,
                                float* __restrict__ sel) {
    int lane = threadIdx.x & 63;
    int wave = blockIdx.x * (blockDim.x >> 6) + (threadIdx.x >> 6);
    if (wave >= NSEL) return;
    int idx = sel_row(wave, users, items, negs);
    int beg = rowptr[idx], end = rowptr[idx + 1];
    float acc = 0.f;
    int j = beg;
    for (; j + 3 < end; j += 4) {
        int2 e0 = edges[j], e1 = edges[j+1], e2 = edges[j+2], e3 = edges[j+3];
        float x0 = bf2f(h[(size_t)(e0.x & COLMASK) * EMBED + lane]);
        float x1 = bf2f(h[(size_t)(e1.x & COLMASK) * EMBED + lane]);
        float x2 = bf2f(h[(size_t)(e2.x & COLMASK) * EMBED + lane]);
        float x3 = bf2f(h[(size_t)(e3.x & COLMASK) * EMBED + lane]);
        acc += bf2f((ushort16)(e0.y & 0xFFFF)) * x0;
        acc += bf2f((ushort16)(e1.y & 0xFFFF)) * x1;
        acc += bf2f((ushort16)(e2.y & 0xFFFF)) * x2;
        acc += bf2f((ushort16)(e3.y & 0xFFFF)) * x3;
    }
    for (; j < end; ++j) {
        int2 e = edges[j];
        acc += bf2f((ushort16)(e.y & 0xFFFF)) * bf2f(h[(size_t)(e.x & COLMASK) * EMBED + lane]);
    }
    sel[(size_t)wave * EMBED + lane] += acc;
}

// ------------------------------------------------- sel accumulate ---------
__global__ void sel_init_kernel(const float* __restrict__ h,
                                const int* __restrict__ users,
                                const int* __restrict__ items,
                                const int* __restrict__ negs,
                                float* __restrict__ sel) {
    int tid = blockIdx.x * blockDim.x + threadIdx.x;
    if (tid >= NSEL * EMBED) return;
    int i = tid >> 6, d = tid & 63;
    int idx = sel_row(i, users, items, negs);
    sel[tid] = h[(size_t)idx * EMBED + d];
}

__global__ void sel_add_bf16_kernel(const ushort16* __restrict__ h,
                                    const int* __restrict__ users,
                                    const int* __restrict__ items,
                                    const int* __restrict__ negs,
                                    float* __restrict__ sel) {
    int tid = blockIdx.x * blockDim.x + threadIdx.x;
    if (tid >= NSEL * EMBED) return;
    int i = tid >> 6, d = tid & 63;
    int idx = sel_row(i, users, items, negs);
    sel[tid] += bf2f(h[(size_t)idx * EMBED + d]);
}

// --------------------------------------- fallback (atomic) path -----------
__global__ void spmm_kernel(const float* __restrict__ src, float* __restrict__ dst,
                            const int* __restrict__ erow, const int* __restrict__ ecol,
                            const float* __restrict__ evalv, int n_edges) {
    int lane  = threadIdx.x & 63;
    int wave  = blockIdx.x * (blockDim.x >> 6) + (threadIdx.x >> 6);
    int nwave = gridDim.x * (blockDim.x >> 6);
    for (int e = wave; e < n_edges; e += nwave) {
        int   r = erow[e];
        int   c = ecol[e];
        float v = evalv[e];
        float x = src[(size_t)c * EMBED + lane];
        atomicAdd(&dst[(size_t)r * EMBED + lane], v * x);
    }
}

__global__ void spmm_filtered_kernel(const float* __restrict__ src, float* __restrict__ dst,
                                     const int* __restrict__ erow, const int* __restrict__ ecol,
                                     const float* __restrict__ evalv,
                                     const unsigned int* __restrict__ bm, int n_edges) {
    int lane  = threadIdx.x & 63;
    int wave  = blockIdx.x * (blockDim.x >> 6) + (threadIdx.x >> 6);
    int nwave = gridDim.x * (blockDim.x >> 6);
    for (int e = wave; e < n_edges; e += nwave) {
        int r = erow[e];
        if (!((bm[r >> 5] >> (r & 31)) & 1u)) continue;
        int   c = ecol[e];
        float v = evalv[e];
        float x = src[(size_t)c * EMBED + lane];
        atomicAdd(&dst[(size_t)r * EMBED + lane], v * x);
    }
}

__global__ void bitmap_build_kernel(const int* __restrict__ users,
                                    const int* __restrict__ items,
                                    const int* __restrict__ negs,
                                    unsigned int* __restrict__ bm) {
    int i = blockIdx.x * blockDim.x + threadIdx.x;
    if (i >= NSEL) return;
    int idx = sel_row(i, users, items, negs);
    atomicOr(&bm[idx >> 5], 1u << (idx & 31));
}

__global__ void sel_accum_kernel(const float* __restrict__ h,
                                 const int* __restrict__ users,
                                 const int* __restrict__ items,
                                 const int* __restrict__ negs,
                                 float* __restrict__ sel, int init) {
    int tid = blockIdx.x * blockDim.x + threadIdx.x;
    if (tid >= NSEL * EMBED) return;
    int i = tid >> 6, d = tid & 63;
    int idx = sel_row(i, users, items, negs);
    float v = h[(size_t)idx * EMBED + d];
    if (init) sel[tid] = v;
    else      sel[tid] += v;
}

// -------------------------------------------------------- sentence encode --
__global__ void sent_kernel(const int* __restrict__ qwords,
                            const float* __restrict__ word_w,
                            const float* __restrict__ Win,  const float* __restrict__ bin,
                            const float* __restrict__ Wout, const float* __restrict__ bout,
                            float* __restrict__ qenc) {
    __shared__ float x[QLEN][EMBED];
    __shared__ float qkv[QLEN][3*EMBED];
    __shared__ float ctx[QLEN][EMBED];
    __shared__ float mctx[EMBED];
    int b = blockIdx.x;
    int t = threadIdx.x;   // 0..127

    for (int j = t; j < QLEN*EMBED; j += 128) {
        int q = j >> 6, d = j & 63;
        int w = qwords[b*QLEN + q];
        x[q][d] = word_w[(size_t)w * EMBED + d];
    }
    __syncthreads();

    for (int j = t; j < QLEN*192; j += 128) {
        int q = j / 192, o = j % 192;
        float acc = bin[o];
        const float* wrow = &Win[o*EMBED];
        #pragma unroll
        for (int d = 0; d < EMBED; ++d) acc += x[q][d] * wrow[d];
        qkv[q][o] = acc;
    }
    __syncthreads();

    if (t < 4*QLEN) {
        int h = t / QLEN, i = t % QLEN;
        float sc[QLEN];
        float mx = -1e30f;
        #pragma unroll
        for (int k = 0; k < QLEN; ++k) {
            float s = 0.f;
            #pragma unroll
            for (int d = 0; d < 16; ++d)
                s += qkv[i][h*16 + d] * qkv[k][EMBED + h*16 + d];
            s *= 0.25f;
            sc[k] = s;
            mx = fmaxf(mx, s);
        }
        float denom = 0.f;
        #pragma unroll
        for (int k = 0; k < QLEN; ++k) { sc[k] = expf(sc[k] - mx); denom += sc[k]; }
        float inv = 1.0f / denom;
        #pragma unroll
        for (int d = 0; d < 16; ++d) {
            float acc = 0.f;
            #pragma unroll
            for (int k = 0; k < QLEN; ++k)
                acc += sc[k] * qkv[k][2*EMBED + h*16 + d];
            ctx[i][h*16 + d] = acc * inv;
        }
    }
    __syncthreads();

    if (t < EMBED) {
        float acc = 0.f;
        #pragma unroll
        for (int q = 0; q < QLEN; ++q) acc += ctx[q][t];
        mctx[t] = acc * (1.0f/QLEN);
    }
    __syncthreads();

    if (t < EMBED) {
        float acc = bout[t];
        const float* wrow = &Wout[t*EMBED];
        #pragma unroll
        for (int d = 0; d < EMBED; ++d) acc += mctx[d] * wrow[d];
        qenc[b*EMBED + t] = acc;
    }
}

// ----------------------------------------------------------------- losses --
__device__ __forceinline__ float log_sigmoid(float x) {
    float l = log1pf(expf(-fabsf(x)));
    return x >= 0.f ? -l : x - l;
}
__device__ __forceinline__ float wred(float v) {
    #pragma unroll
    for (int off = 32; off; off >>= 1) v += __shfl_xor(v, off);
    return v;
}

__global__ void loss_kernel(const float* __restrict__ sel,
                            const float* __restrict__ qenc,
                            float* __restrict__ out) {
    int b = blockIdx.x;
    int d = threadIdx.x;   // 0..63
    const float scale = 0.25f;
    float u   = sel[(size_t)b*EMBED + d] * scale;
    float pos = sel[(size_t)(BATCH + b)*EMBED + d] * scale;
    float p   = qenc[b*EMBED + d] + 0.1f * u;

    float s_up = wred(u * pos);
    float s_pp = wred(p * pos);
    float nu[NNEG], np_[NNEG];
    #pragma unroll
    for (int n = 0; n < NNEG; ++n) {
        float ng = sel[(size_t)(2*BATCH + b*NNEG + n)*EMBED + d] * scale;
        nu[n]  = wred(u * ng);
        np_[n] = wred(p * ng);
    }
    if (d == 0) {
        float cf = 0.f, srch_neg = 0.f;
        #pragma unroll
        for (int n = 0; n < NNEG; ++n) {
            cf       += -log_sigmoid(s_up - nu[n]);
            srch_neg += -log_sigmoid(-np_[n]);
        }
        float res = cf * (1.0f/(BATCH*NNEG))
                  + (-log_sigmoid(s_pp)) * (1.0f/BATCH)
                  + srch_neg * (1.0f/(BATCH*NNEG));
        atomicAdd(out, res);
    }
}

// ---------------------------------------------------------------- launch ---
extern "C" void kernel_launch(void* const* d_in, const int* in_sizes, int n_in,
                              void* d_out, int out_size, void* d_ws, size_t ws_size,
                              hipStream_t stream) {
    const float* entity_w   = (const float*)d_in[0];
    const float* word_w     = (const float*)d_in[1];
    const float* in_proj_w  = (const float*)d_in[2];
    const float* in_proj_b  = (const float*)d_in[3];
    const float* out_proj_w = (const float*)d_in[4];
    const float* out_proj_b = (const float*)d_in[5];
    const float* edge_val   = (const float*)d_in[6];
    const int*   users      = (const int*)d_in[7];
    const int*   items      = (const int*)d_in[8];
    const int*   qwords     = (const int*)d_in[9];
    const int*   neg_items  = (const int*)d_in[10];
    const int*   edge_row   = (const int*)d_in[11];
    const int*   edge_col   = (const int*)d_in[12];
    float* out = (float*)d_out;

    const size_t HN  = (size_t)N_ENTITY * EMBED;       // 12.8M elems
    const size_t HNB = HN * sizeof(ushort16);          // 25.6 MB (bf16 buffer)
    const size_t EB  = sizeof(int2) * (size_t)N_EDGES; // 51.2 MB

    size_t need = EB                                   // ebuf2
                + EB                                   // region A (ebuf -> e16+h1)
                + HNB                                  // h2
                + sizeof(float) * (size_t)NSEL * EMBED // sel
                + sizeof(float) * (size_t)BATCH * EMBED// qenc
                + sizeof(int) * (size_t)(N_ENTITY + 1) // rowptr
                + sizeof(unsigned int) * (size_t)BM_WORDS;

    hipMemsetAsync(out, 0, sizeof(float) * out_size, stream);

    if (ws_size >= need) {
        char* base = (char*)d_ws;
        int2*      ebuf2 = (int2*)base;
        int2*      ebuf  = (int2*)(base + EB);                 // region A
        ushort16*  e16   = (ushort16*)(base + EB);             // alias post-sort
        ushort16*  h1    = (ushort16*)(base + EB + HNB);       // alias post-sort
        char* p = base + 2 * EB;
        ushort16*  h2    = (ushort16*)p;     p += HNB;
        float*     sel   = (float*)p;        p += sizeof(float) * (size_t)NSEL * EMBED;
        float*     qenc  = (float*)p;        p += sizeof(float) * (size_t)BATCH * EMBED;
        int*       rowptr = (int*)p;         p += sizeof(int) * (size_t)(N_ENTITY + 1);
        unsigned int* bmNeed = (unsigned int*)p;
        // build scratch overlaid on h2 (dead until spmm L2 writes needed rows)
        int* bucket_cnt = (int*)h2;
        int* bstart     = bucket_cnt + NBUCKET;
        int* blockBase  = bstart + NBUCKET + 1;

        hipMemsetAsync(bucket_cnt, 0, sizeof(int) * NBUCKET, stream);
        hipMemsetAsync(bmNeed, 0, sizeof(unsigned int) * BM_WORDS, stream);

        // --- atomic-free CSR build (combined int2 stream) ---
        part_hist_kernel<<<NBLK_PART, 256, 0, stream>>>(edge_row, bucket_cnt, blockBase);
        bucket_scan_kernel<<<1, 256, 0, stream>>>(bucket_cnt, bstart);
        part_scatter_kernel<<<NBLK_PART, 256, 0, stream>>>(
            edge_row, edge_col, edge_val, bstart, blockBase, ebuf);
        bucket_sort_kernel<<<NBUCKET, BROWS, 0, stream>>>(ebuf, bstart, ebuf2, rowptr);

        need_build_kernel<<<(NSEL + 3) / 4, 256, 0, stream>>>(
            users, items, neg_items, rowptr, ebuf2, bmNeed);

        // entity -> bf16 (overwrites dead ebuf region)
        conv_bf16_kernel<<<(N_ENTITY * EMBED / 4 + 255) / 256, 256, 0, stream>>>(
            entity_w, e16);

        // --- layer 0 (f32 precision) ---
        sel_init_kernel<<<(NSEL * EMBED) / 256, 256, 0, stream>>>(
            entity_w, users, items, neg_items, sel);

        // --- layer 1: full ---
        spmm_bf16_kernel<0><<<2048, 256, 0, stream>>>(e16, h1, rowptr, ebuf2, nullptr);
        sel_add_bf16_kernel<<<(NSEL * EMBED) / 256, 256, 0, stream>>>(
            h1, users, items, neg_items, sel);

        // --- layer 2: only rows needed downstream ---
        spmm_bf16_kernel<1><<<2048, 256, 0, stream>>>(h1, h2, rowptr, ebuf2, bmNeed);
        sel_add_bf16_kernel<<<(NSEL * EMBED) / 256, 256, 0, stream>>>(
            h2, users, items, neg_items, sel);

        // --- layer 3: direct pull into sel ---
        sel_pull_kernel<<<(NSEL + 3) / 4, 256, 0, stream>>>(
            h2, users, items, neg_items, rowptr, ebuf2, sel);

        sent_kernel<<<BATCH, 128, 0, stream>>>(qwords, word_w, in_proj_w, in_proj_b,
                                               out_proj_w, out_proj_b, qenc);
        loss_kernel<<<BATCH, 64, 0, stream>>>(sel, qenc, out);
    } else {
        // -------- fallback: atomic path (~105 MB ws) --------
        float* hA   = (float*)d_ws;
        float* hB   = hA + HN;
        float* sel  = hB + HN;
        float* qenc = sel + (size_t)NSEL * EMBED;
        unsigned int* bm = (unsigned int*)(qenc + (size_t)BATCH * EMBED);

        hipMemsetAsync(bm, 0, sizeof(unsigned int) * BM_WORDS, stream);
        bitmap_build_kernel<<<(NSEL + 255) / 256, 256, 0, stream>>>(users, items, neg_items, bm);
        sel_accum_kernel<<<(NSEL * EMBED) / 256, 256, 0, stream>>>(
            entity_w, users, items, neg_items, sel, 1);
        hipMemsetAsync(hA, 0, HN * sizeof(float), stream);
        spmm_kernel<<<2048, 256, 0, stream>>>(entity_w, hA, edge_row, edge_col, edge_val, N_EDGES);
        sel_accum_kernel<<<(NSEL * EMBED) / 256, 256, 0, stream>>>(
            hA, users, items, neg_items, sel, 0);
        hipMemsetAsync(hB, 0, HN * sizeof(float), stream);
        spmm_kernel<<<2048, 256, 0, stream>>>(hA, hB, edge_row, edge_col, edge_val, N_EDGES);
        sel_accum_kernel<<<(NSEL * EMBED) / 256, 256, 0, stream>>>(
            hB, users, items, neg_items, sel, 0);
        hipMemsetAsync(hA, 0, HN * sizeof(float), stream);
        spmm_filtered_kernel<<<2048, 256, 0, stream>>>(hB, hA, edge_row, edge_col, edge_val, bm, N_EDGES);
        sel_accum_kernel<<<(NSEL * EMBED) / 256, 256, 0, stream>>>(
            hA, users, items, neg_items, sel, 0);
        sent_kernel<<<BATCH, 128, 0, stream>>>(qwords, word_w, in_proj_w, in_proj_b,
                                               out_proj_w, out_proj_b, qenc);
        loss_kernel<<<BATCH, 64, 0, stream>>>(sel, qenc, out);
    }
}

// Round 8
// 608.418 us; speedup vs baseline: 7.6400x; 1.0323x over previous
//
#include <hip/hip_runtime.h>
#include <math.h>

#define N_ENTITY 200000
#define EMBED    64
#define N_EDGES  6400000
#define BATCH    1024
#define QLEN     20
#define NNEG     5
#define NSEL     (BATCH + BATCH + BATCH*NNEG)   // 7168 gathered rows
#define BM_WORDS ((N_ENTITY + 31) / 32)
#define COLMASK  0x3FFFF

#define BROWS     512                                // rows per bucket
#define ROWSH     9
#define NBUCKET   ((N_ENTITY + BROWS - 1) / BROWS)   // 391
#define NBLK_PART 512

typedef unsigned int   uint32;
typedef unsigned short ushort16;

__device__ __forceinline__ ushort16 f2bf(float f) {
    uint32 b = __float_as_uint(f);
    uint32 r = (b + 0x7FFFu + ((b >> 16) & 1u)) >> 16;   // RNE
    return (ushort16)r;
}
__device__ __forceinline__ float bf2f(ushort16 h) {
    return __uint_as_float(((uint32)h) << 16);
}
__device__ __forceinline__ float bflo(uint32 p) { return __uint_as_float(p << 16); }
__device__ __forceinline__ float bfhi(uint32 p) { return __uint_as_float(p & 0xFFFF0000u); }
__device__ __forceinline__ float edgev(int y) { return __uint_as_float(((uint32)y & 0xFFFFu) << 16); }

// ---------------------------------------------- sel helpers ---------------
__device__ __forceinline__ int sel_row(int i, const int* users, const int* items,
                                       const int* negs) {
    if (i < BATCH)        return users[i];
    if (i < 2 * BATCH)    return items[i - BATCH];
    return negs[i - 2 * BATCH];
}

// ------------------------------------------------------ edge partition ----
__global__ void part_hist_kernel(const int* __restrict__ erow,
                                 int* __restrict__ bucket_cnt,
                                 int* __restrict__ blockBase) {
    __shared__ int h[NBUCKET];
    int blk = blockIdx.x, t = threadIdx.x;
    for (int i = t; i < NBUCKET; i += 256) h[i] = 0;
    __syncthreads();
    int per = (N_EDGES + NBLK_PART - 1) / NBLK_PART;
    int s = blk * per, e = min(s + per, N_EDGES);
    for (int j = s + t; j < e; j += 256)
        atomicAdd(&h[erow[j] >> ROWSH], 1);
    __syncthreads();
    for (int i = t; i < NBUCKET; i += 256)
        blockBase[blk * NBUCKET + i] = atomicAdd(&bucket_cnt[i], h[i]);
}

__global__ void bucket_scan_kernel(const int* __restrict__ cnt,
                                   int* __restrict__ bstart) {
    __shared__ int s[256];
    int t = threadIdx.x;
    int i0 = t * 2, i1 = t * 2 + 1;
    int c0 = (i0 < NBUCKET) ? cnt[i0] : 0;
    int c1 = (i1 < NBUCKET) ? cnt[i1] : 0;
    s[t] = c0 + c1; __syncthreads();
    for (int off = 1; off < 256; off <<= 1) {
        int x = (t >= off) ? s[t - off] : 0;
        __syncthreads();
        s[t] += x;
        __syncthreads();
    }
    int excl = t ? s[t - 1] : 0;
    if (i0 <= NBUCKET) { if (i0 < NBUCKET) bstart[i0] = excl; else bstart[NBUCKET] = excl; }
    excl += c0;
    if (i1 <= NBUCKET) { if (i1 < NBUCKET) bstart[i1] = excl; else bstart[NBUCKET] = excl; }
    if (t == 255) bstart[NBUCKET] = s[255];   // = N_EDGES
}

// scatter into bucket-grouped combined int2 stream
__global__ void part_scatter_kernel(const int* __restrict__ erow,
                                    const int* __restrict__ ecol,
                                    const float* __restrict__ evalv,
                                    const int* __restrict__ bstart,
                                    const int* __restrict__ blockBase,
                                    int2* __restrict__ ebuf) {
    __shared__ int cur[NBUCKET];
    int blk = blockIdx.x, t = threadIdx.x;
    for (int i = t; i < NBUCKET; i += 256)
        cur[i] = bstart[i] + blockBase[blk * NBUCKET + i];
    __syncthreads();
    int per = (N_EDGES + NBLK_PART - 1) / NBLK_PART;
    int s = blk * per, e = min(s + per, N_EDGES);
    int j = s + t;
    for (; j + 256 < e; j += 512) {
        int   r0 = erow[j],       r1 = erow[j + 256];
        int   c0 = ecol[j],       c1 = ecol[j + 256];
        float v0 = evalv[j],      v1 = evalv[j + 256];
        int p0 = atomicAdd(&cur[r0 >> ROWSH], 1);
        int p1 = atomicAdd(&cur[r1 >> ROWSH], 1);
        ebuf[p0] = make_int2(c0 | ((r0 & (BROWS-1)) << 18), (int)f2bf(v0));
        ebuf[p1] = make_int2(c1 | ((r1 & (BROWS-1)) << 18), (int)f2bf(v1));
    }
    for (; j < e; j += 256) {
        int   r = erow[j];
        int   c = ecol[j];
        float v = evalv[j];
        int pos = atomicAdd(&cur[r >> ROWSH], 1);
        ebuf[pos] = make_int2(c | ((r & (BROWS-1)) << 18), (int)f2bf(v));
    }
}

// --------------------------- bucket-local counting sort -> exact CSR ------
__global__ void bucket_sort_kernel(const int2* __restrict__ ebuf,
                                   const int* __restrict__ bstart,
                                   int2* __restrict__ ebuf2,
                                   int* __restrict__ rowptr) {
    __shared__ int cur[BROWS];
    int b = blockIdx.x, t = threadIdx.x;   // t in [0,512)
    int beg = bstart[b], end = bstart[b + 1];
    cur[t] = 0;
    __syncthreads();
    for (int j = beg + t; j < end; j += BROWS)
        atomicAdd(&cur[((unsigned)ebuf[j].x) >> 18], 1);
    __syncthreads();
    int own = cur[t];
    __syncthreads();
    cur[t] = own;
    __syncthreads();
    for (int off = 1; off < BROWS; off <<= 1) {
        int x = (t >= off) ? cur[t - off] : 0;
        __syncthreads();
        cur[t] += x;
        __syncthreads();
    }
    int excl = cur[t] - own;
    __syncthreads();
    int r = (b << ROWSH) + t;
    if (r <= N_ENTITY) rowptr[r] = beg + excl;
    cur[t] = beg + excl;
    __syncthreads();
    for (int j = beg + t; j < end; j += BROWS) {
        int2 e = ebuf[j];
        int pos = atomicAdd(&cur[((unsigned)e.x) >> 18], 1);   // LDS atomic
        ebuf2[pos] = e;
    }
}

// ---------------------- needed-rows bitmap (sel rows + their neighbors) ---
__global__ void need_build_kernel(const int* __restrict__ users,
                                  const int* __restrict__ items,
                                  const int* __restrict__ negs,
                                  const int* __restrict__ rowptr,
                                  const int2* __restrict__ edges,
                                  unsigned int* __restrict__ bm) {
    int lane = threadIdx.x & 63;
    int wave = blockIdx.x * (blockDim.x >> 6) + (threadIdx.x >> 6);
    if (wave >= NSEL) return;
    int idx = sel_row(wave, users, items, negs);
    if (lane == 0) atomicOr(&bm[idx >> 5], 1u << (idx & 31));
    int beg = rowptr[idx], end = rowptr[idx + 1];
    for (int j = beg + lane; j < end; j += 64) {
        int c = edges[j].x & COLMASK;
        atomicOr(&bm[c >> 5], 1u << (c & 31));
    }
}

// ----------------------------------------------- entity -> bf16 convert ---
__global__ void conv_bf16_kernel(const float* __restrict__ src,
                                 ushort16* __restrict__ dst) {
    int i = (blockIdx.x * blockDim.x + threadIdx.x) * 4;
    if (i >= N_ENTITY * EMBED) return;
    float4 v = *(const float4*)&src[i];
    uint32 p0 = (uint32)f2bf(v.x) | ((uint32)f2bf(v.y) << 16);
    uint32 p1 = (uint32)f2bf(v.z) | ((uint32)f2bf(v.w) << 16);
    *(uint2*)&dst[i] = make_uint2(p0, p1);
}

// --------------------------------------------------- bf16 CSR SpMM --------
// Each 32-lane half takes a CONTIGUOUS half of the row's edges and runs an
// 8-deep gather unroll (16 gathers in flight per wave), then 4-deep, then
// scalar cleanup.
template<int FILTER>
__global__ void spmm_bf16_kernel(const ushort16* __restrict__ src,
                                 ushort16* __restrict__ dst,
                                 const int* __restrict__ rowptr,
                                 const int2* __restrict__ edges,
                                 const unsigned int* __restrict__ bm) {
    int lane = threadIdx.x & 63;
    int half = lane >> 5;
    int l2   = lane & 31;
    int wave  = blockIdx.x * (blockDim.x >> 6) + (threadIdx.x >> 6);
    int nwave = gridDim.x * (blockDim.x >> 6);
    for (int row = wave; row < N_ENTITY; row += nwave) {
        if (FILTER && !((bm[row >> 5] >> (row & 31)) & 1u)) continue;
        int beg = rowptr[row], end = rowptr[row + 1];
        int cnt = end - beg;
        int h0  = cnt - (cnt >> 1);               // ceil half for half 0
        int s   = beg + half * h0;
        int e   = half ? end : (beg + h0);
        float ax = 0.f, ay = 0.f;
        int j = s;
        for (; j + 7 < e; j += 8) {
            int2 e0 = edges[j],   e1 = edges[j+1], e2 = edges[j+2], e3 = edges[j+3];
            int2 e4 = edges[j+4], e5 = edges[j+5], e6 = edges[j+6], e7 = edges[j+7];
            uint32 p0 = *(const uint32*)&src[(size_t)(e0.x & COLMASK) * EMBED + l2 * 2];
            uint32 p1 = *(const uint32*)&src[(size_t)(e1.x & COLMASK) * EMBED + l2 * 2];
            uint32 p2 = *(const uint32*)&src[(size_t)(e2.x & COLMASK) * EMBED + l2 * 2];
            uint32 p3 = *(const uint32*)&src[(size_t)(e3.x & COLMASK) * EMBED + l2 * 2];
            uint32 p4 = *(const uint32*)&src[(size_t)(e4.x & COLMASK) * EMBED + l2 * 2];
            uint32 p5 = *(const uint32*)&src[(size_t)(e5.x & COLMASK) * EMBED + l2 * 2];
            uint32 p6 = *(const uint32*)&src[(size_t)(e6.x & COLMASK) * EMBED + l2 * 2];
            uint32 p7 = *(const uint32*)&src[(size_t)(e7.x & COLMASK) * EMBED + l2 * 2];
            float v0 = edgev(e0.y), v1 = edgev(e1.y), v2 = edgev(e2.y), v3 = edgev(e3.y);
            float v4 = edgev(e4.y), v5 = edgev(e5.y), v6 = edgev(e6.y), v7 = edgev(e7.y);
            ax += v0 * bflo(p0);  ay += v0 * bfhi(p0);
            ax += v1 * bflo(p1);  ay += v1 * bfhi(p1);
            ax += v2 * bflo(p2);  ay += v2 * bfhi(p2);
            ax += v3 * bflo(p3);  ay += v3 * bfhi(p3);
            ax += v4 * bflo(p4);  ay += v4 * bfhi(p4);
            ax += v5 * bflo(p5);  ay += v5 * bfhi(p5);
            ax += v6 * bflo(p6);  ay += v6 * bfhi(p6);
            ax += v7 * bflo(p7);  ay += v7 * bfhi(p7);
        }
        for (; j + 3 < e; j += 4) {
            int2 e0 = edges[j], e1 = edges[j+1], e2 = edges[j+2], e3 = edges[j+3];
            uint32 p0 = *(const uint32*)&src[(size_t)(e0.x & COLMASK) * EMBED + l2 * 2];
            uint32 p1 = *(const uint32*)&src[(size_t)(e1.x & COLMASK) * EMBED + l2 * 2];
            uint32 p2 = *(const uint32*)&src[(size_t)(e2.x & COLMASK) * EMBED + l2 * 2];
            uint32 p3 = *(const uint32*)&src[(size_t)(e3.x & COLMASK) * EMBED + l2 * 2];
            float v0 = edgev(e0.y), v1 = edgev(e1.y), v2 = edgev(e2.y), v3 = edgev(e3.y);
            ax += v0 * bflo(p0);  ay += v0 * bfhi(p0);
            ax += v1 * bflo(p1);  ay += v1 * bfhi(p1);
            ax += v2 * bflo(p2);  ay += v2 * bfhi(p2);
            ax += v3 * bflo(p3);  ay += v3 * bfhi(p3);
        }
        for (; j < e; ++j) {
            int2 ed = edges[j];
            float v = edgev(ed.y);
            uint32 p = *(const uint32*)&src[(size_t)(ed.x & COLMASK) * EMBED + l2 * 2];
            ax += v * bflo(p);
            ay += v * bfhi(p);
        }
        ax += __shfl_xor(ax, 32);
        ay += __shfl_xor(ay, 32);
        if (half == 0) {
            uint32 packed = (uint32)f2bf(ax) | ((uint32)f2bf(ay) << 16);
            *(uint32*)&dst[(size_t)row * EMBED + l2 * 2] = packed;
        }
    }
}

// layer-3 direct pull: sel[i] += sum_j val * h2[col]   (h2 bf16)
__global__ void sel_pull_kernel(const ushort16* __restrict__ h,
                                const int* __restrict__ users,
                                const int* __restrict__ items,
                                const int* __restrict__ negs,
                                const int* __restrict__ rowptr,
                                const int2* __restrict__ edges,
                                float* __restrict__ sel) {
    int lane = threadIdx.x & 63;
    int wave = blockIdx.x * (blockDim.x >> 6) + (threadIdx.x >> 6);
    if (wave >= NSEL) return;
    int idx = sel_row(wave, users, items, negs);
    int beg = rowptr[idx], end = rowptr[idx + 1];
    float acc = 0.f;
    int j = beg;
    for (; j + 7 < end; j += 8) {
        int2 e0 = edges[j],   e1 = edges[j+1], e2 = edges[j+2], e3 = edges[j+3];
        int2 e4 = edges[j+4], e5 = edges[j+5], e6 = edges[j+6], e7 = edges[j+7];
        float x0 = bf2f(h[(size_t)(e0.x & COLMASK) * EMBED + lane]);
        float x1 = bf2f(h[(size_t)(e1.x & COLMASK) * EMBED + lane]);
        float x2 = bf2f(h[(size_t)(e2.x & COLMASK) * EMBED + lane]);
        float x3 = bf2f(h[(size_t)(e3.x & COLMASK) * EMBED + lane]);
        float x4 = bf2f(h[(size_t)(e4.x & COLMASK) * EMBED + lane]);
        float x5 = bf2f(h[(size_t)(e5.x & COLMASK) * EMBED + lane]);
        float x6 = bf2f(h[(size_t)(e6.x & COLMASK) * EMBED + lane]);
        float x7 = bf2f(h[(size_t)(e7.x & COLMASK) * EMBED + lane]);
        acc += edgev(e0.y) * x0;
        acc += edgev(e1.y) * x1;
        acc += edgev(e2.y) * x2;
        acc += edgev(e3.y) * x3;
        acc += edgev(e4.y) * x4;
        acc += edgev(e5.y) * x5;
        acc += edgev(e6.y) * x6;
        acc += edgev(e7.y) * x7;
    }
    for (; j < end; ++j) {
        int2 e = edges[j];
        acc += edgev(e.y) * bf2f(h[(size_t)(e.x & COLMASK) * EMBED + lane]);
    }
    sel[(size_t)wave * EMBED + lane] += acc;
}

// ------------------------------------------------- sel accumulate ---------
__global__ void sel_init_kernel(const float* __restrict__ h,
                                const int* __restrict__ users,
                                const int* __restrict__ items,
                                const int* __restrict__ negs,
                                float* __restrict__ sel) {
    int tid = blockIdx.x * blockDim.x + threadIdx.x;
    if (tid >= NSEL * EMBED) return;
    int i = tid >> 6, d = tid & 63;
    int idx = sel_row(i, users, items, negs);
    sel[tid] = h[(size_t)idx * EMBED + d];
}

__global__ void sel_add_bf16_kernel(const ushort16* __restrict__ h,
                                    const int* __restrict__ users,
                                    const int* __restrict__ items,
                                    const int* __restrict__ negs,
                                    float* __restrict__ sel) {
    int tid = blockIdx.x * blockDim.x + threadIdx.x;
    if (tid >= NSEL * EMBED) return;
    int i = tid >> 6, d = tid & 63;
    int idx = sel_row(i, users, items, negs);
    sel[tid] += bf2f(h[(size_t)idx * EMBED + d]);
}

// --------------------------------------- fallback (atomic) path -----------
__global__ void spmm_kernel(const float* __restrict__ src, float* __restrict__ dst,
                            const int* __restrict__ erow, const int* __restrict__ ecol,
                            const float* __restrict__ evalv, int n_edges) {
    int lane  = threadIdx.x & 63;
    int wave  = blockIdx.x * (blockDim.x >> 6) + (threadIdx.x >> 6);
    int nwave = gridDim.x * (blockDim.x >> 6);
    for (int e = wave; e < n_edges; e += nwave) {
        int   r = erow[e];
        int   c = ecol[e];
        float v = evalv[e];
        float x = src[(size_t)c * EMBED + lane];
        atomicAdd(&dst[(size_t)r * EMBED + lane], v * x);
    }
}

__global__ void spmm_filtered_kernel(const float* __restrict__ src, float* __restrict__ dst,
                                     const int* __restrict__ erow, const int* __restrict__ ecol,
                                     const float* __restrict__ evalv,
                                     const unsigned int* __restrict__ bm, int n_edges) {
    int lane  = threadIdx.x & 63;
    int wave  = blockIdx.x * (blockDim.x >> 6) + (threadIdx.x >> 6);
    int nwave = gridDim.x * (blockDim.x >> 6);
    for (int e = wave; e < n_edges; e += nwave) {
        int r = erow[e];
        if (!((bm[r >> 5] >> (r & 31)) & 1u)) continue;
        int   c = ecol[e];
        float v = evalv[e];
        float x = src[(size_t)c * EMBED + lane];
        atomicAdd(&dst[(size_t)r * EMBED + lane], v * x);
    }
}

__global__ void bitmap_build_kernel(const int* __restrict__ users,
                                    const int* __restrict__ items,
                                    const int* __restrict__ negs,
                                    unsigned int* __restrict__ bm) {
    int i = blockIdx.x * blockDim.x + threadIdx.x;
    if (i >= NSEL) return;
    int idx = sel_row(i, users, items, negs);
    atomicOr(&bm[idx >> 5], 1u << (idx & 31));
}

__global__ void sel_accum_kernel(const float* __restrict__ h,
                                 const int* __restrict__ users,
                                 const int* __restrict__ items,
                                 const int* __restrict__ negs,
                                 float* __restrict__ sel, int init) {
    int tid = blockIdx.x * blockDim.x + threadIdx.x;
    if (tid >= NSEL * EMBED) return;
    int i = tid >> 6, d = tid & 63;
    int idx = sel_row(i, users, items, negs);
    float v = h[(size_t)idx * EMBED + d];
    if (init) sel[tid] = v;
    else      sel[tid] += v;
}

// -------------------------------------------------------- sentence encode --
__global__ void sent_kernel(const int* __restrict__ qwords,
                            const float* __restrict__ word_w,
                            const float* __restrict__ Win,  const float* __restrict__ bin,
                            const float* __restrict__ Wout, const float* __restrict__ bout,
                            float* __restrict__ qenc) {
    __shared__ float x[QLEN][EMBED];
    __shared__ float qkv[QLEN][3*EMBED];
    __shared__ float ctx[QLEN][EMBED];
    __shared__ float mctx[EMBED];
    int b = blockIdx.x;
    int t = threadIdx.x;   // 0..127

    for (int j = t; j < QLEN*EMBED; j += 128) {
        int q = j >> 6, d = j & 63;
        int w = qwords[b*QLEN + q];
        x[q][d] = word_w[(size_t)w * EMBED + d];
    }
    __syncthreads();

    for (int j = t; j < QLEN*192; j += 128) {
        int q = j / 192, o = j % 192;
        float acc = bin[o];
        const float* wrow = &Win[o*EMBED];
        #pragma unroll
        for (int d = 0; d < EMBED; ++d) acc += x[q][d] * wrow[d];
        qkv[q][o] = acc;
    }
    __syncthreads();

    if (t < 4*QLEN) {
        int h = t / QLEN, i = t % QLEN;
        float sc[QLEN];
        float mx = -1e30f;
        #pragma unroll
        for (int k = 0; k < QLEN; ++k) {
            float s = 0.f;
            #pragma unroll
            for (int d = 0; d < 16; ++d)
                s += qkv[i][h*16 + d] * qkv[k][EMBED + h*16 + d];
            s *= 0.25f;
            sc[k] = s;
            mx = fmaxf(mx, s);
        }
        float denom = 0.f;
        #pragma unroll
        for (int k = 0; k < QLEN; ++k) { sc[k] = expf(sc[k] - mx); denom += sc[k]; }
        float inv = 1.0f / denom;
        #pragma unroll
        for (int d = 0; d < 16; ++d) {
            float acc = 0.f;
            #pragma unroll
            for (int k = 0; k < QLEN; ++k)
                acc += sc[k] * qkv[k][2*EMBED + h*16 + d];
            ctx[i][h*16 + d] = acc * inv;
        }
    }
    __syncthreads();

    if (t < EMBED) {
        float acc = 0.f;
        #pragma unroll
        for (int q = 0; q < QLEN; ++q) acc += ctx[q][t];
        mctx[t] = acc * (1.0f/QLEN);
    }
    __syncthreads();

    if (t < EMBED) {
        float acc = bout[t];
        const float* wrow = &Wout[t*EMBED];
        #pragma unroll
        for (int d = 0; d < EMBED; ++d) acc += mctx[d] * wrow[d];
        qenc[b*EMBED + t] = acc;
    }
}

// ----------------------------------------------------------------- losses --
__device__ __forceinline__ float log_sigmoid(float x) {
    float l = log1pf(expf(-fabsf(x)));
    return x >= 0.f ? -l : x - l;
}
__device__ __forceinline__ float wred(float v) {
    #pragma unroll
    for (int off = 32; off; off >>= 1) v += __shfl_xor(v, off);
    return v;
}

__global__ void loss_kernel(const float* __restrict__ sel,
                            const float* __restrict__ qenc,
                            float* __restrict__ out) {
    int b = blockIdx.x;
    int d = threadIdx.x;   // 0..63
    const float scale = 0.25f;
    float u   = sel[(size_t)b*EMBED + d] * scale;
    float pos = sel[(size_t)(BATCH + b)*EMBED + d] * scale;
    float p   = qenc[b*EMBED + d] + 0.1f * u;

    float s_up = wred(u * pos);
    float s_pp = wred(p * pos);
    float nu[NNEG], np_[NNEG];
    #pragma unroll
    for (int n = 0; n < NNEG; ++n) {
        float ng = sel[(size_t)(2*BATCH + b*NNEG + n)*EMBED + d] * scale;
        nu[n]  = wred(u * ng);
        np_[n] = wred(p * ng);
    }
    if (d == 0) {
        float cf = 0.f, srch_neg = 0.f;
        #pragma unroll
        for (int n = 0; n < NNEG; ++n) {
            cf       += -log_sigmoid(s_up - nu[n]);
            srch_neg += -log_sigmoid(-np_[n]);
        }
        float res = cf * (1.0f/(BATCH*NNEG))
                  + (-log_sigmoid(s_pp)) * (1.0f/BATCH)
                  + srch_neg * (1.0f/(BATCH*NNEG));
        atomicAdd(out, res);
    }
}

// ---------------------------------------------------------------- launch ---
extern "C" void kernel_launch(void* const* d_in, const int* in_sizes, int n_in,
                              void* d_out, int out_size, void* d_ws, size_t ws_size,
                              hipStream_t stream) {
    const float* entity_w   = (const float*)d_in[0];
    const float* word_w     = (const float*)d_in[1];
    const float* in_proj_w  = (const float*)d_in[2];
    const float* in_proj_b  = (const float*)d_in[3];
    const float* out_proj_w = (const float*)d_in[4];
    const float* out_proj_b = (const float*)d_in[5];
    const float* edge_val   = (const float*)d_in[6];
    const int*   users      = (const int*)d_in[7];
    const int*   items      = (const int*)d_in[8];
    const int*   qwords     = (const int*)d_in[9];
    const int*   neg_items  = (const int*)d_in[10];
    const int*   edge_row   = (const int*)d_in[11];
    const int*   edge_col   = (const int*)d_in[12];
    float* out = (float*)d_out;

    const size_t HN  = (size_t)N_ENTITY * EMBED;       // 12.8M elems
    const size_t HNB = HN * sizeof(ushort16);          // 25.6 MB (bf16 buffer)
    const size_t EB  = sizeof(int2) * (size_t)N_EDGES; // 51.2 MB

    size_t need = EB                                   // ebuf2
                + EB                                   // region A (ebuf -> e16+h1)
                + HNB                                  // h2
                + sizeof(float) * (size_t)NSEL * EMBED // sel
                + sizeof(float) * (size_t)BATCH * EMBED// qenc
                + sizeof(int) * (size_t)(N_ENTITY + 1) // rowptr
                + sizeof(unsigned int) * (size_t)BM_WORDS;

    hipMemsetAsync(out, 0, sizeof(float) * out_size, stream);

    if (ws_size >= need) {
        char* base = (char*)d_ws;
        int2*      ebuf2 = (int2*)base;
        int2*      ebuf  = (int2*)(base + EB);                 // region A
        ushort16*  e16   = (ushort16*)(base + EB);             // alias post-sort
        ushort16*  h1    = (ushort16*)(base + EB + HNB);       // alias post-sort
        char* p = base + 2 * EB;
        ushort16*  h2    = (ushort16*)p;     p += HNB;
        float*     sel   = (float*)p;        p += sizeof(float) * (size_t)NSEL * EMBED;
        float*     qenc  = (float*)p;        p += sizeof(float) * (size_t)BATCH * EMBED;
        int*       rowptr = (int*)p;         p += sizeof(int) * (size_t)(N_ENTITY + 1);
        unsigned int* bmNeed = (unsigned int*)p;
        // build scratch overlaid on h2 (dead until spmm L2 writes needed rows)
        int* bucket_cnt = (int*)h2;
        int* bstart     = bucket_cnt + NBUCKET;
        int* blockBase  = bstart + NBUCKET + 1;

        hipMemsetAsync(bucket_cnt, 0, sizeof(int) * NBUCKET, stream);
        hipMemsetAsync(bmNeed, 0, sizeof(unsigned int) * BM_WORDS, stream);

        // --- atomic-free CSR build (combined int2 stream) ---
        part_hist_kernel<<<NBLK_PART, 256, 0, stream>>>(edge_row, bucket_cnt, blockBase);
        bucket_scan_kernel<<<1, 256, 0, stream>>>(bucket_cnt, bstart);
        part_scatter_kernel<<<NBLK_PART, 256, 0, stream>>>(
            edge_row, edge_col, edge_val, bstart, blockBase, ebuf);
        bucket_sort_kernel<<<NBUCKET, BROWS, 0, stream>>>(ebuf, bstart, ebuf2, rowptr);

        need_build_kernel<<<(NSEL + 3) / 4, 256, 0, stream>>>(
            users, items, neg_items, rowptr, ebuf2, bmNeed);

        // entity -> bf16 (overwrites dead ebuf region)
        conv_bf16_kernel<<<(N_ENTITY * EMBED / 4 + 255) / 256, 256, 0, stream>>>(
            entity_w, e16);

        // --- layer 0 (f32 precision) ---
        sel_init_kernel<<<(NSEL * EMBED) / 256, 256, 0, stream>>>(
            entity_w, users, items, neg_items, sel);

        // --- layer 1: full ---
        spmm_bf16_kernel<0><<<2048, 256, 0, stream>>>(e16, h1, rowptr, ebuf2, nullptr);
        sel_add_bf16_kernel<<<(NSEL * EMBED) / 256, 256, 0, stream>>>(
            h1, users, items, neg_items, sel);

        // --- layer 2: only rows needed downstream ---
        spmm_bf16_kernel<1><<<2048, 256, 0, stream>>>(h1, h2, rowptr, ebuf2, bmNeed);
        sel_add_bf16_kernel<<<(NSEL * EMBED) / 256, 256, 0, stream>>>(
            h2, users, items, neg_items, sel);

        // --- layer 3: direct pull into sel ---
        sel_pull_kernel<<<(NSEL + 3) / 4, 256, 0, stream>>>(
            h2, users, items, neg_items, rowptr, ebuf2, sel);

        sent_kernel<<<BATCH, 128, 0, stream>>>(qwords, word_w, in_proj_w, in_proj_b,
                                               out_proj_w, out_proj_b, qenc);
        loss_kernel<<<BATCH, 64, 0, stream>>>(sel, qenc, out);
    } else {
        // -------- fallback: atomic path (~105 MB ws) --------
        float* hA   = (float*)d_ws;
        float* hB   = hA + HN;
        float* sel  = hB + HN;
        float* qenc = sel + (size_t)NSEL * EMBED;
        unsigned int* bm = (unsigned int*)(qenc + (size_t)BATCH * EMBED);

        hipMemsetAsync(bm, 0, sizeof(unsigned int) * BM_WORDS, stream);
        bitmap_build_kernel<<<(NSEL + 255) / 256, 256, 0, stream>>>(users, items, neg_items, bm);
        sel_accum_kernel<<<(NSEL * EMBED) / 256, 256, 0, stream>>>(
            entity_w, users, items, neg_items, sel, 1);
        hipMemsetAsync(hA, 0, HN * sizeof(float), stream);
        spmm_kernel<<<2048, 256, 0, stream>>>(entity_w, hA, edge_row, edge_col, edge_val, N_EDGES);
        sel_accum_kernel<<<(NSEL * EMBED) / 256, 256, 0, stream>>>(
            hA, users, items, neg_items, sel, 0);
        hipMemsetAsync(hB, 0, HN * sizeof(float), stream);
        spmm_kernel<<<2048, 256, 0, stream>>>(hA, hB, edge_row, edge_col, edge_val, N_EDGES);
        sel_accum_kernel<<<(NSEL * EMBED) / 256, 256, 0, stream>>>(
            hB, users, items, neg_items, sel, 0);
        hipMemsetAsync(hA, 0, HN * sizeof(float), stream);
        spmm_filtered_kernel<<<2048, 256, 0, stream>>>(hB, hA, edge_row, edge_col, edge_val, bm, N_EDGES);
        sel_accum_kernel<<<(NSEL * EMBED) / 256, 256, 0, stream>>>(
            hA, users, items, neg_items, sel, 0);
        sent_kernel<<<BATCH, 128, 0, stream>>>(qwords, word_w, in_proj_w, in_proj_b,
                                               out_proj_w, out_proj_b, qenc);
        loss_kernel<<<BATCH, 64, 0, stream>>>(sel, qenc, out);
    }
}

// Round 9
// 557.081 us; speedup vs baseline: 8.3440x; 1.0922x over previous
//
#include <hip/hip_runtime.h>
#include <math.h>

#define N_ENTITY 200000
#define EMBED    64
#define N_EDGES  6400000
#define BATCH    1024
#define QLEN     20
#define NNEG     5
#define NSEL     (BATCH + BATCH + BATCH*NNEG)   // 7168 gathered rows
#define BM_WORDS ((N_ENTITY + 31) / 32)
#define COLMASK  0x3FFFF

#define BROWS     512                                // rows per bucket
#define ROWSH     9
#define NBUCKET   ((N_ENTITY + BROWS - 1) / BROWS)   // 391
#define NBLK_PART 512

typedef unsigned int   uint32;
typedef unsigned short ushort16;

__device__ __forceinline__ ushort16 f2bf(float f) {
    uint32 b = __float_as_uint(f);
    uint32 r = (b + 0x7FFFu + ((b >> 16) & 1u)) >> 16;   // RNE
    return (ushort16)r;
}
__device__ __forceinline__ float bf2f(ushort16 h) {
    return __uint_as_float(((uint32)h) << 16);
}
__device__ __forceinline__ float bflo(uint32 p) { return __uint_as_float(p << 16); }
__device__ __forceinline__ float bfhi(uint32 p) { return __uint_as_float(p & 0xFFFF0000u); }
__device__ __forceinline__ float edgev(int y) { return __uint_as_float(((uint32)y & 0xFFFFu) << 16); }

// ---------------------------------------------- sel helpers ---------------
__device__ __forceinline__ int sel_row(int i, const int* users, const int* items,
                                       const int* negs) {
    if (i < BATCH)        return users[i];
    if (i < 2 * BATCH)    return items[i - BATCH];
    return negs[i - 2 * BATCH];
}

// ------------------------------------------------------ edge partition ----
__global__ void part_hist_kernel(const int* __restrict__ erow,
                                 int* __restrict__ bucket_cnt,
                                 int* __restrict__ blockBase) {
    __shared__ int h[NBUCKET];
    int blk = blockIdx.x, t = threadIdx.x;
    for (int i = t; i < NBUCKET; i += 256) h[i] = 0;
    __syncthreads();
    int per = (N_EDGES + NBLK_PART - 1) / NBLK_PART;
    int s = blk * per, e = min(s + per, N_EDGES);
    for (int j = s + t; j < e; j += 256)
        atomicAdd(&h[erow[j] >> ROWSH], 1);
    __syncthreads();
    for (int i = t; i < NBUCKET; i += 256)
        blockBase[blk * NBUCKET + i] = atomicAdd(&bucket_cnt[i], h[i]);
}

__global__ void bucket_scan_kernel(const int* __restrict__ cnt,
                                   int* __restrict__ bstart) {
    __shared__ int s[256];
    int t = threadIdx.x;
    int i0 = t * 2, i1 = t * 2 + 1;
    int c0 = (i0 < NBUCKET) ? cnt[i0] : 0;
    int c1 = (i1 < NBUCKET) ? cnt[i1] : 0;
    s[t] = c0 + c1; __syncthreads();
    for (int off = 1; off < 256; off <<= 1) {
        int x = (t >= off) ? s[t - off] : 0;
        __syncthreads();
        s[t] += x;
        __syncthreads();
    }
    int excl = t ? s[t - 1] : 0;
    if (i0 <= NBUCKET) { if (i0 < NBUCKET) bstart[i0] = excl; else bstart[NBUCKET] = excl; }
    excl += c0;
    if (i1 <= NBUCKET) { if (i1 < NBUCKET) bstart[i1] = excl; else bstart[NBUCKET] = excl; }
    if (t == 255) bstart[NBUCKET] = s[255];   // = N_EDGES
}

// scatter into bucket-grouped combined int2 stream
__global__ void part_scatter_kernel(const int* __restrict__ erow,
                                    const int* __restrict__ ecol,
                                    const float* __restrict__ evalv,
                                    const int* __restrict__ bstart,
                                    const int* __restrict__ blockBase,
                                    int2* __restrict__ ebuf) {
    __shared__ int cur[NBUCKET];
    int blk = blockIdx.x, t = threadIdx.x;
    for (int i = t; i < NBUCKET; i += 256)
        cur[i] = bstart[i] + blockBase[blk * NBUCKET + i];
    __syncthreads();
    int per = (N_EDGES + NBLK_PART - 1) / NBLK_PART;
    int s = blk * per, e = min(s + per, N_EDGES);
    int j = s + t;
    for (; j + 256 < e; j += 512) {
        int   r0 = erow[j],       r1 = erow[j + 256];
        int   c0 = ecol[j],       c1 = ecol[j + 256];
        float v0 = evalv[j],      v1 = evalv[j + 256];
        int p0 = atomicAdd(&cur[r0 >> ROWSH], 1);
        int p1 = atomicAdd(&cur[r1 >> ROWSH], 1);
        ebuf[p0] = make_int2(c0 | ((r0 & (BROWS-1)) << 18), (int)f2bf(v0));
        ebuf[p1] = make_int2(c1 | ((r1 & (BROWS-1)) << 18), (int)f2bf(v1));
    }
    for (; j < e; j += 256) {
        int   r = erow[j];
        int   c = ecol[j];
        float v = evalv[j];
        int pos = atomicAdd(&cur[r >> ROWSH], 1);
        ebuf[pos] = make_int2(c | ((r & (BROWS-1)) << 18), (int)f2bf(v));
    }
}

// --------------------------- bucket-local counting sort -> exact CSR ------
__global__ void bucket_sort_kernel(const int2* __restrict__ ebuf,
                                   const int* __restrict__ bstart,
                                   int2* __restrict__ ebuf2,
                                   int* __restrict__ rowptr) {
    __shared__ int cur[BROWS];
    int b = blockIdx.x, t = threadIdx.x;   // t in [0,512)
    int beg = bstart[b], end = bstart[b + 1];
    cur[t] = 0;
    __syncthreads();
    for (int j = beg + t; j < end; j += BROWS)
        atomicAdd(&cur[((unsigned)ebuf[j].x) >> 18], 1);
    __syncthreads();
    int own = cur[t];
    __syncthreads();
    cur[t] = own;
    __syncthreads();
    for (int off = 1; off < BROWS; off <<= 1) {
        int x = (t >= off) ? cur[t - off] : 0;
        __syncthreads();
        cur[t] += x;
        __syncthreads();
    }
    int excl = cur[t] - own;
    __syncthreads();
    int r = (b << ROWSH) + t;
    if (r <= N_ENTITY) rowptr[r] = beg + excl;
    cur[t] = beg + excl;
    __syncthreads();
    for (int j = beg + t; j < end; j += BROWS) {
        int2 e = ebuf[j];
        int pos = atomicAdd(&cur[((unsigned)e.x) >> 18], 1);   // LDS atomic
        ebuf2[pos] = e;
    }
}

// ---------------------- needed-rows bitmap (sel rows + their neighbors) ---
__global__ void need_build_kernel(const int* __restrict__ users,
                                  const int* __restrict__ items,
                                  const int* __restrict__ negs,
                                  const int* __restrict__ rowptr,
                                  const int2* __restrict__ edges,
                                  unsigned int* __restrict__ bm) {
    int lane = threadIdx.x & 63;
    int wave = blockIdx.x * (blockDim.x >> 6) + (threadIdx.x >> 6);
    if (wave >= NSEL) return;
    int idx = sel_row(wave, users, items, negs);
    if (lane == 0) atomicOr(&bm[idx >> 5], 1u << (idx & 31));
    int beg = rowptr[idx], end = rowptr[idx + 1];
    for (int j = beg + lane; j < end; j += 64) {
        int c = edges[j].x & COLMASK;
        atomicOr(&bm[c >> 5], 1u << (c & 31));
    }
}

// ----------------------------------------------- entity -> bf16 convert ---
__global__ void conv_bf16_kernel(const float* __restrict__ src,
                                 ushort16* __restrict__ dst) {
    int i = (blockIdx.x * blockDim.x + threadIdx.x) * 4;
    if (i >= N_ENTITY * EMBED) return;
    float4 v = *(const float4*)&src[i];
    uint32 p0 = (uint32)f2bf(v.x) | ((uint32)f2bf(v.y) << 16);
    uint32 p1 = (uint32)f2bf(v.z) | ((uint32)f2bf(v.w) << 16);
    *(uint2*)&dst[i] = make_uint2(p0, p1);
}

// --------------------------------------------------- bf16 CSR SpMM --------
template<int FILTER>
__global__ void spmm_bf16_kernel(const ushort16* __restrict__ src,
                                 ushort16* __restrict__ dst,
                                 const int* __restrict__ rowptr,
                                 const int2* __restrict__ edges,
                                 const unsigned int* __restrict__ bm) {
    int lane = threadIdx.x & 63;
    int half = lane >> 5;
    int l2   = lane & 31;
    int wave  = blockIdx.x * (blockDim.x >> 6) + (threadIdx.x >> 6);
    int nwave = gridDim.x * (blockDim.x >> 6);
    for (int row = wave; row < N_ENTITY; row += nwave) {
        if (FILTER && !((bm[row >> 5] >> (row & 31)) & 1u)) continue;
        int beg = rowptr[row], end = rowptr[row + 1];
        int cnt = end - beg;
        int h0  = cnt - (cnt >> 1);               // ceil half for half 0
        int s   = beg + half * h0;
        int e   = half ? end : (beg + h0);
        float ax = 0.f, ay = 0.f;
        int j = s;
        for (; j + 7 < e; j += 8) {
            int2 e0 = edges[j],   e1 = edges[j+1], e2 = edges[j+2], e3 = edges[j+3];
            int2 e4 = edges[j+4], e5 = edges[j+5], e6 = edges[j+6], e7 = edges[j+7];
            uint32 p0 = *(const uint32*)&src[(size_t)(e0.x & COLMASK) * EMBED + l2 * 2];
            uint32 p1 = *(const uint32*)&src[(size_t)(e1.x & COLMASK) * EMBED + l2 * 2];
            uint32 p2 = *(const uint32*)&src[(size_t)(e2.x & COLMASK) * EMBED + l2 * 2];
            uint32 p3 = *(const uint32*)&src[(size_t)(e3.x & COLMASK) * EMBED + l2 * 2];
            uint32 p4 = *(const uint32*)&src[(size_t)(e4.x & COLMASK) * EMBED + l2 * 2];
            uint32 p5 = *(const uint32*)&src[(size_t)(e5.x & COLMASK) * EMBED + l2 * 2];
            uint32 p6 = *(const uint32*)&src[(size_t)(e6.x & COLMASK) * EMBED + l2 * 2];
            uint32 p7 = *(const uint32*)&src[(size_t)(e7.x & COLMASK) * EMBED + l2 * 2];
            float v0 = edgev(e0.y), v1 = edgev(e1.y), v2 = edgev(e2.y), v3 = edgev(e3.y);
            float v4 = edgev(e4.y), v5 = edgev(e5.y), v6 = edgev(e6.y), v7 = edgev(e7.y);
            ax += v0 * bflo(p0);  ay += v0 * bfhi(p0);
            ax += v1 * bflo(p1);  ay += v1 * bfhi(p1);
            ax += v2 * bflo(p2);  ay += v2 * bfhi(p2);
            ax += v3 * bflo(p3);  ay += v3 * bfhi(p3);
            ax += v4 * bflo(p4);  ay += v4 * bfhi(p4);
            ax += v5 * bflo(p5);  ay += v5 * bfhi(p5);
            ax += v6 * bflo(p6);  ay += v6 * bfhi(p6);
            ax += v7 * bflo(p7);  ay += v7 * bfhi(p7);
        }
        for (; j + 3 < e; j += 4) {
            int2 e0 = edges[j], e1 = edges[j+1], e2 = edges[j+2], e3 = edges[j+3];
            uint32 p0 = *(const uint32*)&src[(size_t)(e0.x & COLMASK) * EMBED + l2 * 2];
            uint32 p1 = *(const uint32*)&src[(size_t)(e1.x & COLMASK) * EMBED + l2 * 2];
            uint32 p2 = *(const uint32*)&src[(size_t)(e2.x & COLMASK) * EMBED + l2 * 2];
            uint32 p3 = *(const uint32*)&src[(size_t)(e3.x & COLMASK) * EMBED + l2 * 2];
            float v0 = edgev(e0.y), v1 = edgev(e1.y), v2 = edgev(e2.y), v3 = edgev(e3.y);
            ax += v0 * bflo(p0);  ay += v0 * bfhi(p0);
            ax += v1 * bflo(p1);  ay += v1 * bfhi(p1);
            ax += v2 * bflo(p2);  ay += v2 * bfhi(p2);
            ax += v3 * bflo(p3);  ay += v3 * bfhi(p3);
        }
        for (; j < e; ++j) {
            int2 ed = edges[j];
            float v = edgev(ed.y);
            uint32 p = *(const uint32*)&src[(size_t)(ed.x & COLMASK) * EMBED + l2 * 2];
            ax += v * bflo(p);
            ay += v * bfhi(p);
        }
        ax += __shfl_xor(ax, 32);
        ay += __shfl_xor(ay, 32);
        if (half == 0) {
            uint32 packed = (uint32)f2bf(ax) | ((uint32)f2bf(ay) << 16);
            *(uint32*)&dst[(size_t)row * EMBED + l2 * 2] = packed;
        }
    }
}

// layer-3 direct pull: sel[i] += sum_j val * h2[col]   (h2 bf16)
__global__ void sel_pull_kernel(const ushort16* __restrict__ h,
                                const int* __restrict__ users,
                                const int* __restrict__ items,
                                const int* __restrict__ negs,
                                const int* __restrict__ rowptr,
                                const int2* __restrict__ edges,
                                float* __restrict__ sel) {
    int lane = threadIdx.x & 63;
    int wave = blockIdx.x * (blockDim.x >> 6) + (threadIdx.x >> 6);
    if (wave >= NSEL) return;
    int idx = sel_row(wave, users, items, negs);
    int beg = rowptr[idx], end = rowptr[idx + 1];
    float acc = 0.f;
    int j = beg;
    for (; j + 7 < end; j += 8) {
        int2 e0 = edges[j],   e1 = edges[j+1], e2 = edges[j+2], e3 = edges[j+3];
        int2 e4 = edges[j+4], e5 = edges[j+5], e6 = edges[j+6], e7 = edges[j+7];
        float x0 = bf2f(h[(size_t)(e0.x & COLMASK) * EMBED + lane]);
        float x1 = bf2f(h[(size_t)(e1.x & COLMASK) * EMBED + lane]);
        float x2 = bf2f(h[(size_t)(e2.x & COLMASK) * EMBED + lane]);
        float x3 = bf2f(h[(size_t)(e3.x & COLMASK) * EMBED + lane]);
        float x4 = bf2f(h[(size_t)(e4.x & COLMASK) * EMBED + lane]);
        float x5 = bf2f(h[(size_t)(e5.x & COLMASK) * EMBED + lane]);
        float x6 = bf2f(h[(size_t)(e6.x & COLMASK) * EMBED + lane]);
        float x7 = bf2f(h[(size_t)(e7.x & COLMASK) * EMBED + lane]);
        acc += edgev(e0.y) * x0;
        acc += edgev(e1.y) * x1;
        acc += edgev(e2.y) * x2;
        acc += edgev(e3.y) * x3;
        acc += edgev(e4.y) * x4;
        acc += edgev(e5.y) * x5;
        acc += edgev(e6.y) * x6;
        acc += edgev(e7.y) * x7;
    }
    for (; j < end; ++j) {
        int2 e = edges[j];
        acc += edgev(e.y) * bf2f(h[(size_t)(e.x & COLMASK) * EMBED + lane]);
    }
    sel[(size_t)wave * EMBED + lane] += acc;
}

// ------------------------------------------------- sel accumulate ---------
__global__ void sel_init_kernel(const float* __restrict__ h,
                                const int* __restrict__ users,
                                const int* __restrict__ items,
                                const int* __restrict__ negs,
                                float* __restrict__ sel) {
    int tid = blockIdx.x * blockDim.x + threadIdx.x;
    if (tid >= NSEL * EMBED) return;
    int i = tid >> 6, d = tid & 63;
    int idx = sel_row(i, users, items, negs);
    sel[tid] = h[(size_t)idx * EMBED + d];
}

__global__ void sel_add_bf16_kernel(const ushort16* __restrict__ h,
                                    const int* __restrict__ users,
                                    const int* __restrict__ items,
                                    const int* __restrict__ negs,
                                    float* __restrict__ sel) {
    int tid = blockIdx.x * blockDim.x + threadIdx.x;
    if (tid >= NSEL * EMBED) return;
    int i = tid >> 6, d = tid & 63;
    int idx = sel_row(i, users, items, negs);
    sel[tid] += bf2f(h[(size_t)idx * EMBED + d]);
}

// ------------------------------------ sentence encode: qkv projection -----
// One block per batch element; Win/bias/x staged in LDS; conflict-free pads.
__global__ void qkv_kernel(const int* __restrict__ qwords,
                           const float* __restrict__ word_w,
                           const float* __restrict__ Win,
                           const float* __restrict__ bin,
                           float* __restrict__ qkv_g) {
    __shared__ float Wl[192][65];    // 49.9 KB, stride 65 -> conflict-free
    __shared__ float xw[QLEN][65];
    __shared__ float bl[192];
    int b = blockIdx.x, t = threadIdx.x;   // 256 threads

    for (int j = t; j < 192 * EMBED; j += 256) {
        int o = j >> 6, d = j & 63;
        Wl[o][d] = Win[j];
    }
    for (int j = t; j < 192; j += 256) bl[j] = bin[j];
    for (int j = t; j < QLEN * EMBED; j += 256) {
        int q = j >> 6, d = j & 63;
        int w = qwords[b * QLEN + q];
        xw[q][d] = word_w[(size_t)w * EMBED + d];
    }
    __syncthreads();

    for (int j = t; j < QLEN * 192; j += 256) {
        int q = j / 192, o = j % 192;
        float acc = bl[o];
        #pragma unroll
        for (int d = 0; d < EMBED; ++d) acc += xw[q][d] * Wl[o][d];
        qkv_g[(size_t)b * QLEN * 192 + j] = acc;
    }
}

// ------------------------------------- sentence encode: attention + out ---
__global__ void attn_kernel(const float* __restrict__ qkv_g,
                            const float* __restrict__ Wout,
                            const float* __restrict__ bout,
                            float* __restrict__ qenc) {
    __shared__ float qs[QLEN][195];   // stride 195 (== 3 mod 32) -> conflict-free
    __shared__ float ctx[QLEN][68];
    __shared__ float Wl[64][65];
    __shared__ float mctx[EMBED];
    int b = blockIdx.x, t = threadIdx.x;   // 128 threads

    for (int j = t; j < QLEN * 192; j += 128) {
        int q = j / 192, o = j % 192;
        qs[q][o] = qkv_g[(size_t)b * QLEN * 192 + j];
    }
    for (int j = t; j < EMBED * EMBED; j += 128) {
        int o = j >> 6, d = j & 63;
        Wl[o][d] = Wout[j];
    }
    __syncthreads();

    if (t < 4 * QLEN) {
        int h = t / QLEN, i = t % QLEN;
        float sc[QLEN];
        float mx = -1e30f;
        #pragma unroll
        for (int k = 0; k < QLEN; ++k) {
            float s = 0.f;
            #pragma unroll
            for (int d = 0; d < 16; ++d)
                s += qs[i][h*16 + d] * qs[k][EMBED + h*16 + d];
            s *= 0.25f;                       // 1/sqrt(16)
            sc[k] = s;
            mx = fmaxf(mx, s);
        }
        float denom = 0.f;
        #pragma unroll
        for (int k = 0; k < QLEN; ++k) { sc[k] = expf(sc[k] - mx); denom += sc[k]; }
        float inv = 1.0f / denom;
        #pragma unroll
        for (int d = 0; d < 16; ++d) {
            float acc = 0.f;
            #pragma unroll
            for (int k = 0; k < QLEN; ++k)
                acc += sc[k] * qs[k][2*EMBED + h*16 + d];
            ctx[i][h*16 + d] = acc * inv;
        }
    }
    __syncthreads();

    if (t < EMBED) {
        float acc = 0.f;
        #pragma unroll
        for (int q = 0; q < QLEN; ++q) acc += ctx[q][t];
        mctx[t] = acc * (1.0f / QLEN);
    }
    __syncthreads();

    if (t < EMBED) {
        float acc = bout[t];
        #pragma unroll
        for (int d = 0; d < EMBED; ++d) acc += mctx[d] * Wl[t][d];
        qenc[b * EMBED + t] = acc;
    }
}

// --------------------------------------- fallback (atomic) path -----------
__global__ void spmm_kernel(const float* __restrict__ src, float* __restrict__ dst,
                            const int* __restrict__ erow, const int* __restrict__ ecol,
                            const float* __restrict__ evalv, int n_edges) {
    int lane  = threadIdx.x & 63;
    int wave  = blockIdx.x * (blockDim.x >> 6) + (threadIdx.x >> 6);
    int nwave = gridDim.x * (blockDim.x >> 6);
    for (int e = wave; e < n_edges; e += nwave) {
        int   r = erow[e];
        int   c = ecol[e];
        float v = evalv[e];
        float x = src[(size_t)c * EMBED + lane];
        atomicAdd(&dst[(size_t)r * EMBED + lane], v * x);
    }
}

__global__ void spmm_filtered_kernel(const float* __restrict__ src, float* __restrict__ dst,
                                     const int* __restrict__ erow, const int* __restrict__ ecol,
                                     const float* __restrict__ evalv,
                                     const unsigned int* __restrict__ bm, int n_edges) {
    int lane  = threadIdx.x & 63;
    int wave  = blockIdx.x * (blockDim.x >> 6) + (threadIdx.x >> 6);
    int nwave = gridDim.x * (blockDim.x >> 6);
    for (int e = wave; e < n_edges; e += nwave) {
        int r = erow[e];
        if (!((bm[r >> 5] >> (r & 31)) & 1u)) continue;
        int   c = ecol[e];
        float v = evalv[e];
        float x = src[(size_t)c * EMBED + lane];
        atomicAdd(&dst[(size_t)r * EMBED + lane], v * x);
    }
}

__global__ void bitmap_build_kernel(const int* __restrict__ users,
                                    const int* __restrict__ items,
                                    const int* __restrict__ negs,
                                    unsigned int* __restrict__ bm) {
    int i = blockIdx.x * blockDim.x + threadIdx.x;
    if (i >= NSEL) return;
    int idx = sel_row(i, users, items, negs);
    atomicOr(&bm[idx >> 5], 1u << (idx & 31));
}

__global__ void sel_accum_kernel(const float* __restrict__ h,
                                 const int* __restrict__ users,
                                 const int* __restrict__ items,
                                 const int* __restrict__ negs,
                                 float* __restrict__ sel, int init) {
    int tid = blockIdx.x * blockDim.x + threadIdx.x;
    if (tid >= NSEL * EMBED) return;
    int i = tid >> 6, d = tid & 63;
    int idx = sel_row(i, users, items, negs);
    float v = h[(size_t)idx * EMBED + d];
    if (init) sel[tid] = v;
    else      sel[tid] += v;
}

__global__ void sent_kernel(const int* __restrict__ qwords,
                            const float* __restrict__ word_w,
                            const float* __restrict__ Win,  const float* __restrict__ bin,
                            const float* __restrict__ Wout, const float* __restrict__ bout,
                            float* __restrict__ qenc) {
    __shared__ float x[QLEN][EMBED];
    __shared__ float qkv[QLEN][3*EMBED];
    __shared__ float ctx[QLEN][EMBED];
    __shared__ float mctx[EMBED];
    int b = blockIdx.x;
    int t = threadIdx.x;   // 0..127

    for (int j = t; j < QLEN*EMBED; j += 128) {
        int q = j >> 6, d = j & 63;
        int w = qwords[b*QLEN + q];
        x[q][d] = word_w[(size_t)w * EMBED + d];
    }
    __syncthreads();
    for (int j = t; j < QLEN*192; j += 128) {
        int q = j / 192, o = j % 192;
        float acc = bin[o];
        const float* wrow = &Win[o*EMBED];
        #pragma unroll
        for (int d = 0; d < EMBED; ++d) acc += x[q][d] * wrow[d];
        qkv[q][o] = acc;
    }
    __syncthreads();
    if (t < 4*QLEN) {
        int h = t / QLEN, i = t % QLEN;
        float sc[QLEN];
        float mx = -1e30f;
        #pragma unroll
        for (int k = 0; k < QLEN; ++k) {
            float s = 0.f;
            #pragma unroll
            for (int d = 0; d < 16; ++d)
                s += qkv[i][h*16 + d] * qkv[k][EMBED + h*16 + d];
            s *= 0.25f;
            sc[k] = s;
            mx = fmaxf(mx, s);
        }
        float denom = 0.f;
        #pragma unroll
        for (int k = 0; k < QLEN; ++k) { sc[k] = expf(sc[k] - mx); denom += sc[k]; }
        float inv = 1.0f / denom;
        #pragma unroll
        for (int d = 0; d < 16; ++d) {
            float acc = 0.f;
            #pragma unroll
            for (int k = 0; k < QLEN; ++k)
                acc += sc[k] * qkv[k][2*EMBED + h*16 + d];
            ctx[i][h*16 + d] = acc * inv;
        }
    }
    __syncthreads();
    if (t < EMBED) {
        float acc = 0.f;
        #pragma unroll
        for (int q = 0; q < QLEN; ++q) acc += ctx[q][t];
        mctx[t] = acc * (1.0f/QLEN);
    }
    __syncthreads();
    if (t < EMBED) {
        float acc = bout[t];
        const float* wrow = &Wout[t*EMBED];
        #pragma unroll
        for (int d = 0; d < EMBED; ++d) acc += mctx[d] * wrow[d];
        qenc[b*EMBED + t] = acc;
    }
}

// ----------------------------------------------------------------- losses --
__device__ __forceinline__ float log_sigmoid(float x) {
    float l = log1pf(expf(-fabsf(x)));
    return x >= 0.f ? -l : x - l;
}
__device__ __forceinline__ float wred(float v) {
    #pragma unroll
    for (int off = 32; off; off >>= 1) v += __shfl_xor(v, off);
    return v;
}

__global__ void loss_kernel(const float* __restrict__ sel,
                            const float* __restrict__ qenc,
                            float* __restrict__ out) {
    int b = blockIdx.x;
    int d = threadIdx.x;   // 0..63
    const float scale = 0.25f;
    float u   = sel[(size_t)b*EMBED + d] * scale;
    float pos = sel[(size_t)(BATCH + b)*EMBED + d] * scale;
    float p   = qenc[b*EMBED + d] + 0.1f * u;

    float s_up = wred(u * pos);
    float s_pp = wred(p * pos);
    float nu[NNEG], np_[NNEG];
    #pragma unroll
    for (int n = 0; n < NNEG; ++n) {
        float ng = sel[(size_t)(2*BATCH + b*NNEG + n)*EMBED + d] * scale;
        nu[n]  = wred(u * ng);
        np_[n] = wred(p * ng);
    }
    if (d == 0) {
        float cf = 0.f, srch_neg = 0.f;
        #pragma unroll
        for (int n = 0; n < NNEG; ++n) {
            cf       += -log_sigmoid(s_up - nu[n]);
            srch_neg += -log_sigmoid(-np_[n]);
        }
        float res = cf * (1.0f/(BATCH*NNEG))
                  + (-log_sigmoid(s_pp)) * (1.0f/BATCH)
                  + srch_neg * (1.0f/(BATCH*NNEG));
        atomicAdd(out, res);
    }
}

// ---------------------------------------------------------------- launch ---
extern "C" void kernel_launch(void* const* d_in, const int* in_sizes, int n_in,
                              void* d_out, int out_size, void* d_ws, size_t ws_size,
                              hipStream_t stream) {
    const float* entity_w   = (const float*)d_in[0];
    const float* word_w     = (const float*)d_in[1];
    const float* in_proj_w  = (const float*)d_in[2];
    const float* in_proj_b  = (const float*)d_in[3];
    const float* out_proj_w = (const float*)d_in[4];
    const float* out_proj_b = (const float*)d_in[5];
    const float* edge_val   = (const float*)d_in[6];
    const int*   users      = (const int*)d_in[7];
    const int*   items      = (const int*)d_in[8];
    const int*   qwords     = (const int*)d_in[9];
    const int*   neg_items  = (const int*)d_in[10];
    const int*   edge_row   = (const int*)d_in[11];
    const int*   edge_col   = (const int*)d_in[12];
    float* out = (float*)d_out;

    const size_t HN  = (size_t)N_ENTITY * EMBED;       // 12.8M elems
    const size_t HNB = HN * sizeof(ushort16);          // 25.6 MB (bf16 buffer)
    const size_t EB  = sizeof(int2) * (size_t)N_EDGES; // 51.2 MB
    const size_t QKVN = (size_t)BATCH * QLEN * 192;    // 3.93M floats

    size_t need = EB                                   // ebuf2
                + EB                                   // region A (ebuf -> e16+h1)
                + HNB                                  // h2
                + sizeof(float) * (size_t)NSEL * EMBED // sel
                + sizeof(float) * (size_t)BATCH * EMBED// qenc
                + sizeof(int) * (size_t)(N_ENTITY + 1) // rowptr
                + sizeof(unsigned int) * (size_t)BM_WORDS
                + sizeof(float) * QKVN;                // qkv_g

    hipMemsetAsync(out, 0, sizeof(float) * out_size, stream);

    if (ws_size >= need) {
        char* base = (char*)d_ws;
        int2*      ebuf2 = (int2*)base;
        int2*      ebuf  = (int2*)(base + EB);                 // region A
        ushort16*  e16   = (ushort16*)(base + EB);             // alias post-sort
        ushort16*  h1    = (ushort16*)(base + EB + HNB);       // alias post-sort
        char* p = base + 2 * EB;
        ushort16*  h2    = (ushort16*)p;     p += HNB;
        float*     sel   = (float*)p;        p += sizeof(float) * (size_t)NSEL * EMBED;
        float*     qenc  = (float*)p;        p += sizeof(float) * (size_t)BATCH * EMBED;
        int*       rowptr = (int*)p;         p += sizeof(int) * (size_t)(N_ENTITY + 1);
        unsigned int* bmNeed = (unsigned int*)p;  p += sizeof(unsigned int) * (size_t)BM_WORDS;
        float*     qkv_g = (float*)p;
        // build scratch overlaid on h2 (dead until spmm L2 writes needed rows)
        int* bucket_cnt = (int*)h2;
        int* bstart     = bucket_cnt + NBUCKET;
        int* blockBase  = bstart + NBUCKET + 1;

        hipMemsetAsync(bucket_cnt, 0, sizeof(int) * NBUCKET, stream);
        hipMemsetAsync(bmNeed, 0, sizeof(unsigned int) * BM_WORDS, stream);

        // --- atomic-free CSR build (combined int2 stream) ---
        part_hist_kernel<<<NBLK_PART, 256, 0, stream>>>(edge_row, bucket_cnt, blockBase);
        bucket_scan_kernel<<<1, 256, 0, stream>>>(bucket_cnt, bstart);
        part_scatter_kernel<<<NBLK_PART, 256, 0, stream>>>(
            edge_row, edge_col, edge_val, bstart, blockBase, ebuf);
        bucket_sort_kernel<<<NBUCKET, BROWS, 0, stream>>>(ebuf, bstart, ebuf2, rowptr);

        need_build_kernel<<<(NSEL + 3) / 4, 256, 0, stream>>>(
            users, items, neg_items, rowptr, ebuf2, bmNeed);

        // sentence encoder (independent of graph path; run early to overlap)
        qkv_kernel<<<BATCH, 256, 0, stream>>>(qwords, word_w, in_proj_w, in_proj_b, qkv_g);
        attn_kernel<<<BATCH, 128, 0, stream>>>(qkv_g, out_proj_w, out_proj_b, qenc);

        // entity -> bf16 (overwrites dead ebuf region)
        conv_bf16_kernel<<<(N_ENTITY * EMBED / 4 + 255) / 256, 256, 0, stream>>>(
            entity_w, e16);

        // --- layer 0 (f32 precision) ---
        sel_init_kernel<<<(NSEL * EMBED) / 256, 256, 0, stream>>>(
            entity_w, users, items, neg_items, sel);

        // --- layer 1: full ---
        spmm_bf16_kernel<0><<<2048, 256, 0, stream>>>(e16, h1, rowptr, ebuf2, nullptr);
        sel_add_bf16_kernel<<<(NSEL * EMBED) / 256, 256, 0, stream>>>(
            h1, users, items, neg_items, sel);

        // --- layer 2: only rows needed downstream ---
        spmm_bf16_kernel<1><<<2048, 256, 0, stream>>>(h1, h2, rowptr, ebuf2, bmNeed);
        sel_add_bf16_kernel<<<(NSEL * EMBED) / 256, 256, 0, stream>>>(
            h2, users, items, neg_items, sel);

        // --- layer 3: direct pull into sel ---
        sel_pull_kernel<<<(NSEL + 3) / 4, 256, 0, stream>>>(
            h2, users, items, neg_items, rowptr, ebuf2, sel);

        loss_kernel<<<BATCH, 64, 0, stream>>>(sel, qenc, out);
    } else {
        // -------- fallback: atomic path (~105 MB ws) --------
        float* hA   = (float*)d_ws;
        float* hB   = hA + HN;
        float* sel  = hB + HN;
        float* qenc = sel + (size_t)NSEL * EMBED;
        unsigned int* bm = (unsigned int*)(qenc + (size_t)BATCH * EMBED);

        hipMemsetAsync(bm, 0, sizeof(unsigned int) * BM_WORDS, stream);
        bitmap_build_kernel<<<(NSEL + 255) / 256, 256, 0, stream>>>(users, items, neg_items, bm);
        sel_accum_kernel<<<(NSEL * EMBED) / 256, 256, 0, stream>>>(
            entity_w, users, items, neg_items, sel, 1);
        hipMemsetAsync(hA, 0, HN * sizeof(float), stream);
        spmm_kernel<<<2048, 256, 0, stream>>>(entity_w, hA, edge_row, edge_col, edge_val, N_EDGES);
        sel_accum_kernel<<<(NSEL * EMBED) / 256, 256, 0, stream>>>(
            hA, users, items, neg_items, sel, 0);
        hipMemsetAsync(hB, 0, HN * sizeof(float), stream);
        spmm_kernel<<<2048, 256, 0, stream>>>(hA, hB, edge_row, edge_col, edge_val, N_EDGES);
        sel_accum_kernel<<<(NSEL * EMBED) / 256, 256, 0, stream>>>(
            hB, users, items, neg_items, sel, 0);
        hipMemsetAsync(hA, 0, HN * sizeof(float), stream);
        spmm_filtered_kernel<<<2048, 256, 0, stream>>>(hB, hA, edge_row, edge_col, edge_val, bm, N_EDGES);
        sel_accum_kernel<<<(NSEL * EMBED) / 256, 256, 0, stream>>>(
            hA, users, items, neg_items, sel, 0);
        sent_kernel<<<BATCH, 128, 0, stream>>>(qwords, word_w, in_proj_w, in_proj_b,
                                               out_proj_w, out_proj_b, qenc);
        loss_kernel<<<BATCH, 64, 0, stream>>>(sel, qenc, out);
    }
}